// Round 1
// baseline (745.695 us; speedup 1.0000x reference)
//
#include <hip/hip_runtime.h>
#include <math.h>

#define NN 40000
#define EE 640000
#define NG 64

__device__ __forceinline__ float eluf(float x) { return x > 0.f ? x : expm1f(x); }

__global__ void zero_int_kernel(int* __restrict__ p, int n) {
  int i = blockIdx.x * 256 + threadIdx.x;
  if (i < n) p[i] = 0;
}

__global__ void count_deg_kernel(const int* __restrict__ dst, int* __restrict__ deg, int e) {
  int i = blockIdx.x * 256 + threadIdx.x;
  if (i < e) atomicAdd(&deg[dst[i]], 1);
}

__global__ void scan_kernel(const int* __restrict__ deg, int* __restrict__ row_ptr, int n) {
  __shared__ int buf[1024];
  int t = threadIdx.x;
  int run = 0;
  for (int base = 0; base < n; base += 1024) {
    int v = (base + t < n) ? deg[base + t] : 0;
    buf[t] = v;
    __syncthreads();
    for (int off = 1; off < 1024; off <<= 1) {
      int xx = (t >= off) ? buf[t - off] : 0;
      __syncthreads();
      buf[t] += xx;
      __syncthreads();
    }
    if (base + t < n) row_ptr[base + t + 1] = run + buf[t];
    run += buf[1023];
    __syncthreads();
  }
  if (t == 0) row_ptr[0] = 0;
}

__global__ void scatter_kernel(const int* __restrict__ src, const int* __restrict__ dst,
                               int* __restrict__ cursor, int* __restrict__ csr_src, int e) {
  int i = blockIdx.x * 256 + threadIdx.x;
  if (i < e) {
    int d = dst[i];
    int pos = atomicAdd(&cursor[d], 1);
    csr_src[pos] = src[i];
  }
}

// h = x @ W  (FIN=128 fixed), plus al_s/al_d attention projections per node.
template<int OUT>
__global__ __launch_bounds__(256) void gemm_al_kernel(
    const float* __restrict__ x, const float* __restrict__ W,
    const float* __restrict__ a_s, const float* __restrict__ a_d,
    float* __restrict__ h, float* __restrict__ als, float* __restrict__ ald, int n)
{
  __shared__ float Wl[128 * OUT];
  int t = threadIdx.x;
  for (int i = t; i < 128 * OUT; i += 256) Wl[i] = W[i];
  __syncthreads();
  int lane = t & 63, wid = t >> 6;
  int nw = gridDim.x * 4;
  for (int row = blockIdx.x * 4 + wid; row < n; row += nw) {
    float xv0 = x[row * 128 + lane];
    float xv1 = x[row * 128 + 64 + lane];
    if constexpr (OUT == 128) {
      float a0 = 0.f, a1 = 0.f;  // cols 2*lane, 2*lane+1
#pragma unroll
      for (int k = 0; k < 64; ++k) {
        float xk = __shfl(xv0, k);
        float2 w = *reinterpret_cast<const float2*>(&Wl[k * 128 + 2 * lane]);
        a0 = fmaf(xk, w.x, a0); a1 = fmaf(xk, w.y, a1);
      }
#pragma unroll
      for (int k = 0; k < 64; ++k) {
        float xk = __shfl(xv1, k);
        float2 w = *reinterpret_cast<const float2*>(&Wl[(64 + k) * 128 + 2 * lane]);
        a0 = fmaf(xk, w.x, a0); a1 = fmaf(xk, w.y, a1);
      }
      reinterpret_cast<float2*>(h)[row * 64 + lane] = make_float2(a0, a1);
      // head of col o = o>>5 ; o = 2*lane -> head = lane>>4 (16-lane groups)
      float ps = fmaf(a0, a_s[2 * lane], a1 * a_s[2 * lane + 1]);
      float pd = fmaf(a0, a_d[2 * lane], a1 * a_d[2 * lane + 1]);
#pragma unroll
      for (int m = 1; m < 16; m <<= 1) { ps += __shfl_xor(ps, m); pd += __shfl_xor(pd, m); }
      if ((lane & 15) == 0) {
        int hh = lane >> 4;
        als[row * 4 + hh] = ps;
        ald[row * 4 + hh] = pd;
      }
    } else {  // OUT == 32, lanes 32-63 duplicate lanes 0-31
      int col = lane & 31;
      float a0 = 0.f;
#pragma unroll
      for (int k = 0; k < 64; ++k) a0 = fmaf(__shfl(xv0, k), Wl[k * 32 + col], a0);
#pragma unroll
      for (int k = 0; k < 64; ++k) a0 = fmaf(__shfl(xv1, k), Wl[(64 + k) * 32 + col], a0);
      if (lane < 32) h[row * 32 + col] = a0;
      float ps = a0 * a_s[col];
      float pd = a0 * a_d[col];
#pragma unroll
      for (int m = 1; m < 32; m <<= 1) { ps += __shfl_xor(ps, m); pd += __shfl_xor(pd, m); }
      if (lane == 0) { als[row] = ps; ald[row] = pd; }
    }
  }
}

// One wave per dst node: segment softmax over incoming edges + weighted gather
// of h[src], fused with +bias, LayerNorm, ELU.
template<int H, int C>
__global__ __launch_bounds__(256) void aggregate_kernel(
    const float* __restrict__ h, const float* __restrict__ als, const float* __restrict__ ald,
    const int* __restrict__ row_ptr, const int* __restrict__ csr_src,
    const float* __restrict__ bias, const float* __restrict__ ln_g, const float* __restrict__ ln_b,
    float* __restrict__ out, int n)
{
  constexpr int OUT = H * C;
  __shared__ int s_src[4][64];
  __shared__ float s_ex[4][64][H];
  int t = threadIdx.x, lane = t & 63, wid = t >> 6;
  int node = blockIdx.x * 4 + wid;
  if (node >= n) return;
  int start = row_ptr[node], end = row_ptr[node + 1];

  float adl[H];
#pragma unroll
  for (int hh = 0; hh < H; ++hh) adl[hh] = ald[node * H + hh];

  // pass 1: segment max per head
  float mx[H];
#pragma unroll
  for (int hh = 0; hh < H; ++hh) mx[hh] = -INFINITY;
  for (int eb = start; eb < end; eb += 64) {
    int e = eb + lane;
    if (e < end) {
      int s = csr_src[e];
      float av[H];
      if constexpr (H == 4) {
        float4 q = reinterpret_cast<const float4*>(als)[s];
        av[0] = q.x; av[1] = q.y; av[2] = q.z; av[3] = q.w;
      } else av[0] = als[s];
#pragma unroll
      for (int hh = 0; hh < H; ++hh) {
        float v = av[hh] + adl[hh];
        v = v > 0.f ? v : 0.2f * v;
        mx[hh] = fmaxf(mx[hh], v);
      }
    }
  }
#pragma unroll
  for (int hh = 0; hh < H; ++hh)
#pragma unroll
    for (int m = 1; m < 64; m <<= 1) mx[hh] = fmaxf(mx[hh], __shfl_xor(mx[hh], m));

  // pass 2: exp, running sum, and unnormalized weighted aggregation
  float acc0 = 0.f, acc1 = 0.f;
  float ssum[H];
#pragma unroll
  for (int hh = 0; hh < H; ++hh) ssum[hh] = 0.f;

  for (int eb = start; eb < end; eb += 64) {
    int e = eb + lane;
    int s = 0;
    float exv[H];
#pragma unroll
    for (int hh = 0; hh < H; ++hh) exv[hh] = 0.f;
    if (e < end) {
      s = csr_src[e];
      float av[H];
      if constexpr (H == 4) {
        float4 q = reinterpret_cast<const float4*>(als)[s];
        av[0] = q.x; av[1] = q.y; av[2] = q.z; av[3] = q.w;
      } else av[0] = als[s];
#pragma unroll
      for (int hh = 0; hh < H; ++hh) {
        float v = av[hh] + adl[hh];
        v = v > 0.f ? v : 0.2f * v;
        float ex = __expf(v - mx[hh]);
        exv[hh] = ex;
        ssum[hh] += ex;
      }
    }
    s_src[wid][lane] = s;
#pragma unroll
    for (int hh = 0; hh < H; ++hh) s_ex[wid][lane][hh] = exv[hh];
    // wave-synchronous LDS (lockstep within wave; compiler orders ds ops)
    int cnt = end - eb; if (cnt > 64) cnt = 64;
    if constexpr (OUT == 128) {
      int h0 = lane >> 5, h1 = 2 + (lane >> 5);
      for (int j = 0; j < cnt; ++j) {
        int sj = s_src[wid][j];
        float w0 = s_ex[wid][j][h0];
        float w1 = s_ex[wid][j][h1];
        acc0 = fmaf(w0, h[sj * 128 + lane], acc0);
        acc1 = fmaf(w1, h[sj * 128 + 64 + lane], acc1);
      }
    } else {
      int col = lane & 31;
      for (int j = 0; j < cnt; ++j) {
        int sj = s_src[wid][j];
        float w0 = s_ex[wid][j][0];
        acc0 = fmaf(w0, h[sj * 32 + col], acc0);
      }
    }
  }
#pragma unroll
  for (int hh = 0; hh < H; ++hh)
#pragma unroll
    for (int m = 1; m < 64; m <<= 1) ssum[hh] += __shfl_xor(ssum[hh], m);

  if constexpr (OUT == 128) {
    int h0 = lane >> 5, h1 = 2 + (lane >> 5);
    float o0 = acc0 / (ssum[h0] + 1e-16f) + bias[lane];
    float o1 = acc1 / (ssum[h1] + 1e-16f) + bias[lane + 64];
    float red = o0 + o1;
#pragma unroll
    for (int m = 1; m < 64; m <<= 1) red += __shfl_xor(red, m);
    float mu = red * (1.f / 128.f);
    float d0 = o0 - mu, d1 = o1 - mu;
    float sq = d0 * d0 + d1 * d1;
#pragma unroll
    for (int m = 1; m < 64; m <<= 1) sq += __shfl_xor(sq, m);
    float rstd = rsqrtf(sq * (1.f / 128.f) + 1e-5f);
    float y0 = d0 * rstd * ln_g[lane] + ln_b[lane];
    float y1 = d1 * rstd * ln_g[lane + 64] + ln_b[lane + 64];
    out[node * 128 + lane] = eluf(y0);
    out[node * 128 + 64 + lane] = eluf(y1);
  } else {
    int col = lane & 31;
    float o0 = acc0 / (ssum[0] + 1e-16f) + bias[col];
    // lanes 32-63 hold duplicates of 0-31 -> divide reductions by 64
    float red = o0;
#pragma unroll
    for (int m = 1; m < 64; m <<= 1) red += __shfl_xor(red, m);
    float mu = red * (1.f / 64.f);
    float d0 = o0 - mu;
    float sq = d0 * d0;
#pragma unroll
    for (int m = 1; m < 64; m <<= 1) sq += __shfl_xor(sq, m);
    float rstd = rsqrtf(sq * (1.f / 64.f) + 1e-5f);
    float y0 = d0 * rstd * ln_g[col] + ln_b[col];
    if (lane < 32) out[node * 32 + col] = eluf(y0);
  }
}

__device__ __forceinline__ int lower_bound_dev(const int* a, int n, int key) {
  int lo = 0, hi = n;
  while (lo < hi) { int mid = (lo + hi) >> 1; if (a[mid] < key) lo = mid + 1; else hi = mid; }
  return lo;
}

__global__ __launch_bounds__(256) void pool_kernel(const float* __restrict__ x2,
                                                   const int* __restrict__ batch,
                                                   float* __restrict__ hg, int n) {
  int g = blockIdx.x;
  int lo = lower_bound_dev(batch, n, g);
  int hi = lower_bound_dev(batch, n, g + 1);
  int t = threadIdx.x;
  int c = t & 31, r = t >> 5;
  float acc = 0.f;
  for (int i = lo + r; i < hi; i += 8) acc += x2[i * 32 + c];
  __shared__ float red[8][32];
  red[r][c] = acc;
  __syncthreads();
  if (r == 0) {
    float s = 0.f;
#pragma unroll
    for (int k = 0; k < 8; ++k) s += red[k][c];
    float cnt = (float)(hi - lo);
    hg[g * 32 + c] = s / fmaxf(cnt, 1.f);
  }
}

__global__ void fc_kernel(const float* __restrict__ hg,
                          const float* __restrict__ fc1w, const float* __restrict__ fc1b,
                          const float* __restrict__ fc2w, const float* __restrict__ fc2b,
                          float* __restrict__ out) {
  int g = threadIdx.x;
  if (g >= NG) return;
  float v[32];
#pragma unroll
  for (int k = 0; k < 32; ++k) v[k] = hg[g * 32 + k];
  float z[16];
#pragma unroll
  for (int j = 0; j < 16; ++j) {
    float a = fc1b[j];
#pragma unroll
    for (int k = 0; k < 32; ++k) a = fmaf(v[k], fc1w[k * 16 + j], a);
    z[j] = fmaxf(a, 0.f);
  }
#pragma unroll
  for (int o = 0; o < 2; ++o) {
    float a = fc2b[o];
#pragma unroll
    for (int j = 0; j < 16; ++j) a = fmaf(z[j], fc2w[j * 2 + o], a);
    out[g * 2 + o] = a;
  }
}

extern "C" void kernel_launch(void* const* d_in, const int* in_sizes, int n_in,
                              void* d_out, int out_size, void* d_ws, size_t ws_size,
                              hipStream_t stream) {
  const float* x    = (const float*)d_in[0];
  const int*   ei   = (const int*)d_in[1];
  const int*   batch= (const int*)d_in[2];
  const float* W0   = (const float*)d_in[3];
  const float* as0  = (const float*)d_in[4];
  const float* ad0  = (const float*)d_in[5];
  const float* b0   = (const float*)d_in[6];
  const float* ln0g = (const float*)d_in[7];
  const float* ln0b = (const float*)d_in[8];
  const float* W1   = (const float*)d_in[9];
  const float* as1  = (const float*)d_in[10];
  const float* ad1  = (const float*)d_in[11];
  const float* b1   = (const float*)d_in[12];
  const float* ln1g = (const float*)d_in[13];
  const float* ln1b = (const float*)d_in[14];
  const float* W2   = (const float*)d_in[15];
  const float* as2  = (const float*)d_in[16];
  const float* ad2  = (const float*)d_in[17];
  const float* b2   = (const float*)d_in[18];
  const float* ln2g = (const float*)d_in[19];
  const float* ln2b = (const float*)d_in[20];
  const float* fc1w = (const float*)d_in[21];
  const float* fc1b = (const float*)d_in[22];
  const float* fc2w = (const float*)d_in[23];
  const float* fc2b = (const float*)d_in[24];
  float* out = (float*)d_out;

  const int* srce = ei;
  const int* dste = ei + EE;

  float* B1  = (float*)d_ws;                 // N*128
  float* B2  = B1 + (size_t)NN * 128;        // N*128
  float* als = B2 + (size_t)NN * 128;        // N*4
  float* ald = als + (size_t)NN * 4;         // N*4
  float* h2  = ald + (size_t)NN * 4;         // N*32
  float* x2  = h2 + (size_t)NN * 32;         // N*32
  float* hg  = x2 + (size_t)NN * 32;         // 64*32
  int* deg      = (int*)(hg + NG * 32);      // N
  int* row_ptr  = deg + NN;                  // N+1
  int* cursor   = row_ptr + NN + 1;          // N
  int* csr_src  = cursor + NN;               // E

  // CSR build (shared by all 3 layers)
  zero_int_kernel<<<(NN + 255) / 256, 256, 0, stream>>>(deg, NN);
  count_deg_kernel<<<(EE + 255) / 256, 256, 0, stream>>>(dste, deg, EE);
  scan_kernel<<<1, 1024, 0, stream>>>(deg, row_ptr, NN);
  hipMemcpyAsync(cursor, row_ptr, NN * sizeof(int), hipMemcpyDeviceToDevice, stream);
  scatter_kernel<<<(EE + 255) / 256, 256, 0, stream>>>(srce, dste, cursor, csr_src, EE);

  // layer 0
  gemm_al_kernel<128><<<512, 256, 0, stream>>>(x, W0, as0, ad0, B1, als, ald, NN);
  aggregate_kernel<4, 32><<<(NN + 3) / 4, 256, 0, stream>>>(B1, als, ald, row_ptr, csr_src,
                                                            b0, ln0g, ln0b, B2, NN);
  // layer 1
  gemm_al_kernel<128><<<512, 256, 0, stream>>>(B2, W1, as1, ad1, B1, als, ald, NN);
  aggregate_kernel<4, 32><<<(NN + 3) / 4, 256, 0, stream>>>(B1, als, ald, row_ptr, csr_src,
                                                            b1, ln1g, ln1b, B2, NN);
  // layer 2
  gemm_al_kernel<32><<<1024, 256, 0, stream>>>(B2, W2, as2, ad2, h2, als, ald, NN);
  aggregate_kernel<1, 32><<<(NN + 3) / 4, 256, 0, stream>>>(h2, als, ald, row_ptr, csr_src,
                                                            b2, ln2g, ln2b, x2, NN);
  // pool + classifier
  pool_kernel<<<NG, 256, 0, stream>>>(x2, batch, hg, NN);
  fc_kernel<<<1, 64, 0, stream>>>(hg, fc1w, fc1b, fc2w, fc2b, out);
}

// Round 2
// 387.601 us; speedup vs baseline: 1.9239x; 1.9239x over previous
//
#include <hip/hip_runtime.h>
#include <math.h>

#define NN 40000
#define EE 640000
#define NG 64

__device__ __forceinline__ float eluf(float x) { return x > 0.f ? x : expm1f(x); }

typedef const __attribute__((address_space(1))) char gas_char;
typedef __attribute__((address_space(3))) char las_char;

__device__ __forceinline__ void async_copy16(void* l, const void* g) {
  __builtin_amdgcn_global_load_lds((gas_char*)g, (las_char*)l, 16, 0, 0);
}

__global__ void zero_int_kernel(int* __restrict__ p, int n) {
  int i = blockIdx.x * 256 + threadIdx.x;
  if (i < n) p[i] = 0;
}

__global__ void count_deg_kernel(const int* __restrict__ dst, int* __restrict__ deg, int e) {
  int i = blockIdx.x * 256 + threadIdx.x;
  if (i < e) atomicAdd(&deg[dst[i]], 1);
}

__global__ void scan_kernel(const int* __restrict__ deg, int* __restrict__ row_ptr, int n) {
  __shared__ int buf[1024];
  int t = threadIdx.x;
  int run = 0;
  for (int base = 0; base < n; base += 1024) {
    int v = (base + t < n) ? deg[base + t] : 0;
    buf[t] = v;
    __syncthreads();
    for (int off = 1; off < 1024; off <<= 1) {
      int xx = (t >= off) ? buf[t - off] : 0;
      __syncthreads();
      buf[t] += xx;
      __syncthreads();
    }
    if (base + t < n) row_ptr[base + t + 1] = run + buf[t];
    run += buf[1023];
    __syncthreads();
  }
  if (t == 0) row_ptr[0] = 0;
}

__global__ void scatter_kernel(const int* __restrict__ src, const int* __restrict__ dst,
                               int* __restrict__ cursor, int* __restrict__ csr_src, int e) {
  int i = blockIdx.x * 256 + threadIdx.x;
  if (i < e) {
    int d = dst[i];
    int pos = atomicAdd(&cursor[d], 1);
    csr_src[pos] = src[i];
  }
}

// Register-blocked tile GEMM: h = x @ W (K=128 fixed), fused per-row attention
// projections als/ald. Block = 256 threads, tile = 64 rows x OUT cols.
// Per-thread: ROWS x 4 outputs. x tile (32KB) staged once via global_load_lds;
// W staged in double-buffered 32-k chunks.
template<int OUT>
__global__ __launch_bounds__(256, 2) void gemm_al_kernel(
    const float* __restrict__ x, const float* __restrict__ W,
    const float* __restrict__ a_s, const float* __restrict__ a_d,
    float* __restrict__ h, float* __restrict__ als, float* __restrict__ ald)
{
  constexpr int G = OUT / 4;      // col-groups (32 or 8)
  constexpr int ROWS = OUT / 16;  // rows per thread (8 or 2)
  constexpr int H = OUT / 32;     // heads
  constexpr int WPASS = OUT / 32; // 16B-passes per W chunk stage (4 or 1)
  __shared__ float xs[64 * 128];
  __shared__ float ws[2][32 * OUT];

  int t = threadIdx.x;
  int row0 = blockIdx.x * 64;

  // stage x tile: contiguous 32KB
  {
    const char* xg = (const char*)(x + (size_t)row0 * 128);
    char* xl = (char*)xs;
#pragma unroll
    for (int it = 0; it < 8; ++it)
      async_copy16(xl + it * 4096 + t * 16, xg + it * 4096 + t * 16);
  }
  // stage W chunk 0
  {
    const char* wg = (const char*)W;
    char* wl = (char*)ws[0];
#pragma unroll
    for (int p = 0; p < WPASS; ++p)
      async_copy16(wl + p * 4096 + t * 16, wg + p * 4096 + t * 16);
  }
  __syncthreads();

  int cg = t & (G - 1);
  int rg = t / G;
  int r0 = rg * ROWS;
  int c0 = cg * 4;

  float acc[ROWS][4];
#pragma unroll
  for (int r = 0; r < ROWS; ++r)
#pragma unroll
    for (int c = 0; c < 4; ++c) acc[r][c] = 0.f;

  for (int ch = 0; ch < 4; ++ch) {
    if (ch < 3) {  // prefetch next W chunk into other buffer
      const char* wg = (const char*)W + (size_t)(ch + 1) * 32 * OUT * 4;
      char* wl = (char*)ws[(ch + 1) & 1];
#pragma unroll
      for (int p = 0; p < WPASS; ++p)
        async_copy16(wl + p * 4096 + t * 16, wg + p * 4096 + t * 16);
    }
    const float* wc = ws[ch & 1];
    const float* xc = xs + ch * 32;
#pragma unroll
    for (int kk = 0; kk < 32; kk += 4) {
      float4 wv[4];
#pragma unroll
      for (int q = 0; q < 4; ++q)
        wv[q] = *reinterpret_cast<const float4*>(&wc[(kk + q) * OUT + c0]);
#pragma unroll
      for (int r = 0; r < ROWS; ++r) {
        float4 xv = *reinterpret_cast<const float4*>(&xc[(r0 + r) * 128 + kk]);
#pragma unroll
        for (int c = 0; c < 4; ++c) {
          float a = acc[r][c];
          a = fmaf(xv.x, (&wv[0].x)[c], a);
          a = fmaf(xv.y, (&wv[1].x)[c], a);
          a = fmaf(xv.z, (&wv[2].x)[c], a);
          a = fmaf(xv.w, (&wv[3].x)[c], a);
          acc[r][c] = a;
        }
      }
    }
    __syncthreads();
  }

  // write h tile
#pragma unroll
  for (int r = 0; r < ROWS; ++r) {
    float4 hv = make_float4(acc[r][0], acc[r][1], acc[r][2], acc[r][3]);
    *reinterpret_cast<float4*>(&h[(size_t)(row0 + r0 + r) * OUT + c0]) = hv;
  }

  // attention projections: per row, dot over this thread's 4 cols, reduce
  // across the 8 lanes sharing a head (masks 1,2,4).
  float asv[4], adv[4];
#pragma unroll
  for (int c = 0; c < 4; ++c) { asv[c] = a_s[c0 + c]; adv[c] = a_d[c0 + c]; }
  int head = c0 >> 5;
#pragma unroll
  for (int r = 0; r < ROWS; ++r) {
    float ps = acc[r][0] * asv[0] + acc[r][1] * asv[1] + acc[r][2] * asv[2] + acc[r][3] * asv[3];
    float pd = acc[r][0] * adv[0] + acc[r][1] * adv[1] + acc[r][2] * adv[2] + acc[r][3] * adv[3];
#pragma unroll
    for (int m = 1; m < 8; m <<= 1) { ps += __shfl_xor(ps, m); pd += __shfl_xor(pd, m); }
    if ((t & 7) == 0) {
      als[(size_t)(row0 + r0 + r) * H + head] = ps;
      ald[(size_t)(row0 + r0 + r) * H + head] = pd;
    }
  }
}

// One wave per dst node: segment softmax over incoming edges + weighted gather
// of h[src], fused with +bias, LayerNorm, ELU.
template<int H, int C>
__global__ __launch_bounds__(256) void aggregate_kernel(
    const float* __restrict__ h, const float* __restrict__ als, const float* __restrict__ ald,
    const int* __restrict__ row_ptr, const int* __restrict__ csr_src,
    const float* __restrict__ bias, const float* __restrict__ ln_g, const float* __restrict__ ln_b,
    float* __restrict__ out, int n)
{
  constexpr int OUT = H * C;
  __shared__ int s_src[4][64];
  __shared__ float s_ex[4][64][H];
  int t = threadIdx.x, lane = t & 63, wid = t >> 6;
  int node = blockIdx.x * 4 + wid;
  if (node >= n) return;
  int start = row_ptr[node], end = row_ptr[node + 1];

  float adl[H];
#pragma unroll
  for (int hh = 0; hh < H; ++hh) adl[hh] = ald[node * H + hh];

  // pass 1: segment max per head
  float mx[H];
#pragma unroll
  for (int hh = 0; hh < H; ++hh) mx[hh] = -INFINITY;
  for (int eb = start; eb < end; eb += 64) {
    int e = eb + lane;
    if (e < end) {
      int s = csr_src[e];
      float av[H];
      if constexpr (H == 4) {
        float4 q = reinterpret_cast<const float4*>(als)[s];
        av[0] = q.x; av[1] = q.y; av[2] = q.z; av[3] = q.w;
      } else av[0] = als[s];
#pragma unroll
      for (int hh = 0; hh < H; ++hh) {
        float v = av[hh] + adl[hh];
        v = v > 0.f ? v : 0.2f * v;
        mx[hh] = fmaxf(mx[hh], v);
      }
    }
  }
#pragma unroll
  for (int hh = 0; hh < H; ++hh)
#pragma unroll
    for (int m = 1; m < 64; m <<= 1) mx[hh] = fmaxf(mx[hh], __shfl_xor(mx[hh], m));

  // pass 2: exp, running sum, and unnormalized weighted aggregation
  float acc0 = 0.f, acc1 = 0.f;
  float ssum[H];
#pragma unroll
  for (int hh = 0; hh < H; ++hh) ssum[hh] = 0.f;

  for (int eb = start; eb < end; eb += 64) {
    int e = eb + lane;
    int s = 0;
    float exv[H];
#pragma unroll
    for (int hh = 0; hh < H; ++hh) exv[hh] = 0.f;
    if (e < end) {
      s = csr_src[e];
      float av[H];
      if constexpr (H == 4) {
        float4 q = reinterpret_cast<const float4*>(als)[s];
        av[0] = q.x; av[1] = q.y; av[2] = q.z; av[3] = q.w;
      } else av[0] = als[s];
#pragma unroll
      for (int hh = 0; hh < H; ++hh) {
        float v = av[hh] + adl[hh];
        v = v > 0.f ? v : 0.2f * v;
        float ex = __expf(v - mx[hh]);
        exv[hh] = ex;
        ssum[hh] += ex;
      }
    }
    s_src[wid][lane] = s;
#pragma unroll
    for (int hh = 0; hh < H; ++hh) s_ex[wid][lane][hh] = exv[hh];
    int cnt = end - eb; if (cnt > 64) cnt = 64;
    if constexpr (OUT == 128) {
      int h0 = lane >> 5, h1 = 2 + (lane >> 5);
      for (int j = 0; j < cnt; ++j) {
        int sj = s_src[wid][j];
        float w0 = s_ex[wid][j][h0];
        float w1 = s_ex[wid][j][h1];
        acc0 = fmaf(w0, h[sj * 128 + lane], acc0);
        acc1 = fmaf(w1, h[sj * 128 + 64 + lane], acc1);
      }
    } else {
      int col = lane & 31;
      for (int j = 0; j < cnt; ++j) {
        int sj = s_src[wid][j];
        float w0 = s_ex[wid][j][0];
        acc0 = fmaf(w0, h[sj * 32 + col], acc0);
      }
    }
  }
#pragma unroll
  for (int hh = 0; hh < H; ++hh)
#pragma unroll
    for (int m = 1; m < 64; m <<= 1) ssum[hh] += __shfl_xor(ssum[hh], m);

  if constexpr (OUT == 128) {
    int h0 = lane >> 5, h1 = 2 + (lane >> 5);
    float o0 = acc0 / (ssum[h0] + 1e-16f) + bias[lane];
    float o1 = acc1 / (ssum[h1] + 1e-16f) + bias[lane + 64];
    float red = o0 + o1;
#pragma unroll
    for (int m = 1; m < 64; m <<= 1) red += __shfl_xor(red, m);
    float mu = red * (1.f / 128.f);
    float d0 = o0 - mu, d1 = o1 - mu;
    float sq = d0 * d0 + d1 * d1;
#pragma unroll
    for (int m = 1; m < 64; m <<= 1) sq += __shfl_xor(sq, m);
    float rstd = rsqrtf(sq * (1.f / 128.f) + 1e-5f);
    float y0 = d0 * rstd * ln_g[lane] + ln_b[lane];
    float y1 = d1 * rstd * ln_g[lane + 64] + ln_b[lane + 64];
    out[node * 128 + lane] = eluf(y0);
    out[node * 128 + 64 + lane] = eluf(y1);
  } else {
    int col = lane & 31;
    float o0 = acc0 / (ssum[0] + 1e-16f) + bias[col];
    float red = o0;
#pragma unroll
    for (int m = 1; m < 64; m <<= 1) red += __shfl_xor(red, m);
    float mu = red * (1.f / 64.f);
    float d0 = o0 - mu;
    float sq = d0 * d0;
#pragma unroll
    for (int m = 1; m < 64; m <<= 1) sq += __shfl_xor(sq, m);
    float rstd = rsqrtf(sq * (1.f / 64.f) + 1e-5f);
    float y0 = d0 * rstd * ln_g[col] + ln_b[col];
    if (lane < 32) out[node * 32 + col] = eluf(y0);
  }
}

__device__ __forceinline__ int lower_bound_dev(const int* a, int n, int key) {
  int lo = 0, hi = n;
  while (lo < hi) { int mid = (lo + hi) >> 1; if (a[mid] < key) lo = mid + 1; else hi = mid; }
  return lo;
}

__global__ __launch_bounds__(256) void pool_kernel(const float* __restrict__ x2,
                                                   const int* __restrict__ batch,
                                                   float* __restrict__ hg, int n) {
  int g = blockIdx.x;
  int lo = lower_bound_dev(batch, n, g);
  int hi = lower_bound_dev(batch, n, g + 1);
  int t = threadIdx.x;
  int c = t & 31, r = t >> 5;
  float acc = 0.f;
  for (int i = lo + r; i < hi; i += 8) acc += x2[i * 32 + c];
  __shared__ float red[8][32];
  red[r][c] = acc;
  __syncthreads();
  if (r == 0) {
    float s = 0.f;
#pragma unroll
    for (int k = 0; k < 8; ++k) s += red[k][c];
    float cnt = (float)(hi - lo);
    hg[g * 32 + c] = s / fmaxf(cnt, 1.f);
  }
}

__global__ void fc_kernel(const float* __restrict__ hg,
                          const float* __restrict__ fc1w, const float* __restrict__ fc1b,
                          const float* __restrict__ fc2w, const float* __restrict__ fc2b,
                          float* __restrict__ out) {
  int g = threadIdx.x;
  if (g >= NG) return;
  float v[32];
#pragma unroll
  for (int k = 0; k < 32; ++k) v[k] = hg[g * 32 + k];
  float z[16];
#pragma unroll
  for (int j = 0; j < 16; ++j) {
    float a = fc1b[j];
#pragma unroll
    for (int k = 0; k < 32; ++k) a = fmaf(v[k], fc1w[k * 16 + j], a);
    z[j] = fmaxf(a, 0.f);
  }
#pragma unroll
  for (int o = 0; o < 2; ++o) {
    float a = fc2b[o];
#pragma unroll
    for (int j = 0; j < 16; ++j) a = fmaf(z[j], fc2w[j * 2 + o], a);
    out[g * 2 + o] = a;
  }
}

extern "C" void kernel_launch(void* const* d_in, const int* in_sizes, int n_in,
                              void* d_out, int out_size, void* d_ws, size_t ws_size,
                              hipStream_t stream) {
  const float* x    = (const float*)d_in[0];
  const int*   ei   = (const int*)d_in[1];
  const int*   batch= (const int*)d_in[2];
  const float* W0   = (const float*)d_in[3];
  const float* as0  = (const float*)d_in[4];
  const float* ad0  = (const float*)d_in[5];
  const float* b0   = (const float*)d_in[6];
  const float* ln0g = (const float*)d_in[7];
  const float* ln0b = (const float*)d_in[8];
  const float* W1   = (const float*)d_in[9];
  const float* as1  = (const float*)d_in[10];
  const float* ad1  = (const float*)d_in[11];
  const float* b1   = (const float*)d_in[12];
  const float* ln1g = (const float*)d_in[13];
  const float* ln1b = (const float*)d_in[14];
  const float* W2   = (const float*)d_in[15];
  const float* as2  = (const float*)d_in[16];
  const float* ad2  = (const float*)d_in[17];
  const float* b2   = (const float*)d_in[18];
  const float* ln2g = (const float*)d_in[19];
  const float* ln2b = (const float*)d_in[20];
  const float* fc1w = (const float*)d_in[21];
  const float* fc1b = (const float*)d_in[22];
  const float* fc2w = (const float*)d_in[23];
  const float* fc2b = (const float*)d_in[24];
  float* out = (float*)d_out;

  const int* srce = ei;
  const int* dste = ei + EE;

  float* B1  = (float*)d_ws;                 // N*128
  float* B2  = B1 + (size_t)NN * 128;        // N*128
  float* als = B2 + (size_t)NN * 128;        // N*4
  float* ald = als + (size_t)NN * 4;         // N*4
  float* h2  = ald + (size_t)NN * 4;         // N*32
  float* x2  = h2 + (size_t)NN * 32;         // N*32
  float* hg  = x2 + (size_t)NN * 32;         // 64*32
  int* deg      = (int*)(hg + NG * 32);      // N
  int* row_ptr  = deg + NN;                  // N+1
  int* cursor   = row_ptr + NN + 1;          // N
  int* csr_src  = cursor + NN;               // E

  // CSR build (shared by all 3 layers)
  zero_int_kernel<<<(NN + 255) / 256, 256, 0, stream>>>(deg, NN);
  count_deg_kernel<<<(EE + 255) / 256, 256, 0, stream>>>(dste, deg, EE);
  scan_kernel<<<1, 1024, 0, stream>>>(deg, row_ptr, NN);
  hipMemcpyAsync(cursor, row_ptr, NN * sizeof(int), hipMemcpyDeviceToDevice, stream);
  scatter_kernel<<<(EE + 255) / 256, 256, 0, stream>>>(srce, dste, cursor, csr_src, EE);

  // layer 0
  gemm_al_kernel<128><<<625, 256, 0, stream>>>(x, W0, as0, ad0, B1, als, ald);
  aggregate_kernel<4, 32><<<(NN + 3) / 4, 256, 0, stream>>>(B1, als, ald, row_ptr, csr_src,
                                                            b0, ln0g, ln0b, B2, NN);
  // layer 1
  gemm_al_kernel<128><<<625, 256, 0, stream>>>(B2, W1, as1, ad1, B1, als, ald);
  aggregate_kernel<4, 32><<<(NN + 3) / 4, 256, 0, stream>>>(B1, als, ald, row_ptr, csr_src,
                                                            b1, ln1g, ln1b, B2, NN);
  // layer 2
  gemm_al_kernel<32><<<625, 256, 0, stream>>>(B2, W2, as2, ad2, h2, als, ald);
  aggregate_kernel<1, 32><<<(NN + 3) / 4, 256, 0, stream>>>(h2, als, ald, row_ptr, csr_src,
                                                            b2, ln2g, ln2b, x2, NN);
  // pool + classifier
  pool_kernel<<<NG, 256, 0, stream>>>(x2, batch, hg, NN);
  fc_kernel<<<1, 64, 0, stream>>>(hg, fc1w, fc1b, fc2w, fc2b, out);
}

// Round 3
// 323.200 us; speedup vs baseline: 2.3072x; 1.1993x over previous
//
#include <hip/hip_runtime.h>
#include <math.h>

#define NN 40000
#define EE 640000
#define NG 64
#define SCAN_BLOCKS ((NN + 1023) / 1024)

__device__ __forceinline__ float eluf(float x) { return x > 0.f ? x : expm1f(x); }

typedef const __attribute__((address_space(1))) char gas_char;
typedef __attribute__((address_space(3))) char las_char;

__device__ __forceinline__ void async_copy16(void* l, const void* g) {
  __builtin_amdgcn_global_load_lds((gas_char*)g, (las_char*)l, 16, 0, 0);
}

__global__ void zero_int_kernel(int* __restrict__ p, int n) {
  int i = blockIdx.x * 256 + threadIdx.x;
  if (i < n) p[i] = 0;
}

__global__ void count_deg_kernel(const int* __restrict__ dst, int* __restrict__ deg, int e) {
  int i = blockIdx.x * 256 + threadIdx.x;
  if (i < e) atomicAdd(&deg[dst[i]], 1);
}

// Hierarchical scan A: per-block inclusive scan (wave shfl scans), block sums out.
__global__ __launch_bounds__(1024) void scanA_kernel(const int* __restrict__ deg,
                                                     int* __restrict__ row_ptr,
                                                     int* __restrict__ bsum, int n) {
  __shared__ int wsum[16];
  int t = threadIdx.x, lane = t & 63, wid = t >> 6;
  int i = blockIdx.x * 1024 + t;
  int v = (i < n) ? deg[i] : 0;
#pragma unroll
  for (int off = 1; off < 64; off <<= 1) {
    int u = __shfl_up(v, off);
    if (lane >= off) v += u;
  }
  if (lane == 63) wsum[wid] = v;
  __syncthreads();
  if (t < 16) {
    int w = wsum[t];
#pragma unroll
    for (int off = 1; off < 16; off <<= 1) {
      int u = __shfl_up(w, off);
      if (t >= off) w += u;
    }
    wsum[t] = w;
  }
  __syncthreads();
  if (wid > 0) v += wsum[wid - 1];
  if (i < n) row_ptr[i + 1] = v;
  if (t == 1023) bsum[blockIdx.x] = v;
}

// Hierarchical scan B: exclusive scan of block sums (single wave).
__global__ void scanB_kernel(const int* __restrict__ bsum, int* __restrict__ boff, int nb) {
  int lane = threadIdx.x;
  int v = (lane < nb) ? bsum[lane] : 0;
  int orig = v;
#pragma unroll
  for (int off = 1; off < 64; off <<= 1) {
    int u = __shfl_up(v, off);
    if (lane >= off) v += u;
  }
  if (lane < nb) boff[lane] = v - orig;
}

// Hierarchical scan C: add block offsets; also materialize cursor[] = row_ptr[].
__global__ __launch_bounds__(1024) void scanC_kernel(int* __restrict__ row_ptr,
                                                     const int* __restrict__ boff,
                                                     int* __restrict__ cursor, int n) {
  int i = blockIdx.x * 1024 + threadIdx.x;
  if (i < n) {
    int v = row_ptr[i + 1] + boff[i >> 10];
    row_ptr[i + 1] = v;
    if (i + 1 < n) cursor[i + 1] = v;
    if (i == 0) { cursor[0] = 0; row_ptr[0] = 0; }
  }
}

__global__ void scatter_kernel(const int* __restrict__ src, const int* __restrict__ dst,
                               int* __restrict__ cursor, int* __restrict__ csr_src, int e) {
  int i = blockIdx.x * 256 + threadIdx.x;
  if (i < e) {
    int d = dst[i];
    int pos = atomicAdd(&cursor[d], 1);
    csr_src[pos] = src[i];
  }
}

// Register-blocked tile GEMM: h = x @ W (K=128 fixed), fused per-row attention
// projections als/ald. Block = 256 threads, tile = 64 rows x OUT cols.
template<int OUT>
__global__ __launch_bounds__(256, 2) void gemm_al_kernel(
    const float* __restrict__ x, const float* __restrict__ W,
    const float* __restrict__ a_s, const float* __restrict__ a_d,
    float* __restrict__ h, float* __restrict__ als, float* __restrict__ ald)
{
  constexpr int G = OUT / 4;      // col-groups (32 or 8)
  constexpr int ROWS = OUT / 16;  // rows per thread (8 or 2)
  constexpr int H = OUT / 32;     // heads
  constexpr int WPASS = OUT / 32; // 16B-passes per W chunk stage (4 or 1)
  __shared__ float xs[64 * 128];
  __shared__ float ws[2][32 * OUT];

  int t = threadIdx.x;
  int row0 = blockIdx.x * 64;

  {
    const char* xg = (const char*)(x + (size_t)row0 * 128);
    char* xl = (char*)xs;
#pragma unroll
    for (int it = 0; it < 8; ++it)
      async_copy16(xl + it * 4096 + t * 16, xg + it * 4096 + t * 16);
  }
  {
    const char* wg = (const char*)W;
    char* wl = (char*)ws[0];
#pragma unroll
    for (int p = 0; p < WPASS; ++p)
      async_copy16(wl + p * 4096 + t * 16, wg + p * 4096 + t * 16);
  }
  __syncthreads();

  int cg = t & (G - 1);
  int rg = t / G;
  int r0 = rg * ROWS;
  int c0 = cg * 4;

  float acc[ROWS][4];
#pragma unroll
  for (int r = 0; r < ROWS; ++r)
#pragma unroll
    for (int c = 0; c < 4; ++c) acc[r][c] = 0.f;

  for (int ch = 0; ch < 4; ++ch) {
    if (ch < 3) {
      const char* wg = (const char*)W + (size_t)(ch + 1) * 32 * OUT * 4;
      char* wl = (char*)ws[(ch + 1) & 1];
#pragma unroll
      for (int p = 0; p < WPASS; ++p)
        async_copy16(wl + p * 4096 + t * 16, wg + p * 4096 + t * 16);
    }
    const float* wc = ws[ch & 1];
    const float* xc = xs + ch * 32;
#pragma unroll
    for (int kk = 0; kk < 32; kk += 4) {
      float4 wv[4];
#pragma unroll
      for (int q = 0; q < 4; ++q)
        wv[q] = *reinterpret_cast<const float4*>(&wc[(kk + q) * OUT + c0]);
#pragma unroll
      for (int r = 0; r < ROWS; ++r) {
        float4 xv = *reinterpret_cast<const float4*>(&xc[(r0 + r) * 128 + kk]);
#pragma unroll
        for (int c = 0; c < 4; ++c) {
          float a = acc[r][c];
          a = fmaf(xv.x, (&wv[0].x)[c], a);
          a = fmaf(xv.y, (&wv[1].x)[c], a);
          a = fmaf(xv.z, (&wv[2].x)[c], a);
          a = fmaf(xv.w, (&wv[3].x)[c], a);
          acc[r][c] = a;
        }
      }
    }
    __syncthreads();
  }

#pragma unroll
  for (int r = 0; r < ROWS; ++r) {
    float4 hv = make_float4(acc[r][0], acc[r][1], acc[r][2], acc[r][3]);
    *reinterpret_cast<float4*>(&h[(size_t)(row0 + r0 + r) * OUT + c0]) = hv;
  }

  float asv[4], adv[4];
#pragma unroll
  for (int c = 0; c < 4; ++c) { asv[c] = a_s[c0 + c]; adv[c] = a_d[c0 + c]; }
  int head = c0 >> 5;
#pragma unroll
  for (int r = 0; r < ROWS; ++r) {
    float ps = acc[r][0] * asv[0] + acc[r][1] * asv[1] + acc[r][2] * asv[2] + acc[r][3] * asv[3];
    float pd = acc[r][0] * adv[0] + acc[r][1] * adv[1] + acc[r][2] * adv[2] + acc[r][3] * adv[3];
#pragma unroll
    for (int m = 1; m < 8; m <<= 1) { ps += __shfl_xor(ps, m); pd += __shfl_xor(pd, m); }
    if ((t & 7) == 0) {
      als[(size_t)(row0 + r0 + r) * H + head] = ps;
      ald[(size_t)(row0 + r0 + r) * H + head] = pd;
    }
  }
}

// One wave per dst node: segment softmax over incoming edges + weighted gather
// of h[src], fused with +bias, LayerNorm, ELU.
template<int H, int C>
__global__ __launch_bounds__(256) void aggregate_kernel(
    const float* __restrict__ h, const float* __restrict__ als, const float* __restrict__ ald,
    const int* __restrict__ row_ptr, const int* __restrict__ csr_src,
    const float* __restrict__ bias, const float* __restrict__ ln_g, const float* __restrict__ ln_b,
    float* __restrict__ out, int n)
{
  constexpr int OUT = H * C;
  __shared__ int s_src[4][64];
  __shared__ float s_ex[4][64][H];
  int t = threadIdx.x, lane = t & 63, wid = t >> 6;
  int node = blockIdx.x * 4 + wid;
  if (node >= n) return;
  int start = row_ptr[node], end = row_ptr[node + 1];

  float adl[H];
#pragma unroll
  for (int hh = 0; hh < H; ++hh) adl[hh] = ald[node * H + hh];

  float mx[H];
#pragma unroll
  for (int hh = 0; hh < H; ++hh) mx[hh] = -INFINITY;
  for (int eb = start; eb < end; eb += 64) {
    int e = eb + lane;
    if (e < end) {
      int s = csr_src[e];
      float av[H];
      if constexpr (H == 4) {
        float4 q = reinterpret_cast<const float4*>(als)[s];
        av[0] = q.x; av[1] = q.y; av[2] = q.z; av[3] = q.w;
      } else av[0] = als[s];
#pragma unroll
      for (int hh = 0; hh < H; ++hh) {
        float v = av[hh] + adl[hh];
        v = v > 0.f ? v : 0.2f * v;
        mx[hh] = fmaxf(mx[hh], v);
      }
    }
  }
#pragma unroll
  for (int hh = 0; hh < H; ++hh)
#pragma unroll
    for (int m = 1; m < 64; m <<= 1) mx[hh] = fmaxf(mx[hh], __shfl_xor(mx[hh], m));

  float acc0 = 0.f, acc1 = 0.f;
  float ssum[H];
#pragma unroll
  for (int hh = 0; hh < H; ++hh) ssum[hh] = 0.f;

  for (int eb = start; eb < end; eb += 64) {
    int e = eb + lane;
    int s = 0;
    float exv[H];
#pragma unroll
    for (int hh = 0; hh < H; ++hh) exv[hh] = 0.f;
    if (e < end) {
      s = csr_src[e];
      float av[H];
      if constexpr (H == 4) {
        float4 q = reinterpret_cast<const float4*>(als)[s];
        av[0] = q.x; av[1] = q.y; av[2] = q.z; av[3] = q.w;
      } else av[0] = als[s];
#pragma unroll
      for (int hh = 0; hh < H; ++hh) {
        float v = av[hh] + adl[hh];
        v = v > 0.f ? v : 0.2f * v;
        float ex = __expf(v - mx[hh]);
        exv[hh] = ex;
        ssum[hh] += ex;
      }
    }
    s_src[wid][lane] = s;
#pragma unroll
    for (int hh = 0; hh < H; ++hh) s_ex[wid][lane][hh] = exv[hh];
    int cnt = end - eb; if (cnt > 64) cnt = 64;
    if constexpr (OUT == 128) {
      int h0 = lane >> 5, h1 = 2 + (lane >> 5);
      for (int j = 0; j < cnt; ++j) {
        int sj = s_src[wid][j];
        float w0 = s_ex[wid][j][h0];
        float w1 = s_ex[wid][j][h1];
        acc0 = fmaf(w0, h[sj * 128 + lane], acc0);
        acc1 = fmaf(w1, h[sj * 128 + 64 + lane], acc1);
      }
    } else {
      int col = lane & 31;
      for (int j = 0; j < cnt; ++j) {
        int sj = s_src[wid][j];
        float w0 = s_ex[wid][j][0];
        acc0 = fmaf(w0, h[sj * 32 + col], acc0);
      }
    }
  }
#pragma unroll
  for (int hh = 0; hh < H; ++hh)
#pragma unroll
    for (int m = 1; m < 64; m <<= 1) ssum[hh] += __shfl_xor(ssum[hh], m);

  if constexpr (OUT == 128) {
    int h0 = lane >> 5, h1 = 2 + (lane >> 5);
    float o0 = acc0 / (ssum[h0] + 1e-16f) + bias[lane];
    float o1 = acc1 / (ssum[h1] + 1e-16f) + bias[lane + 64];
    float red = o0 + o1;
#pragma unroll
    for (int m = 1; m < 64; m <<= 1) red += __shfl_xor(red, m);
    float mu = red * (1.f / 128.f);
    float d0 = o0 - mu, d1 = o1 - mu;
    float sq = d0 * d0 + d1 * d1;
#pragma unroll
    for (int m = 1; m < 64; m <<= 1) sq += __shfl_xor(sq, m);
    float rstd = rsqrtf(sq * (1.f / 128.f) + 1e-5f);
    float y0 = d0 * rstd * ln_g[lane] + ln_b[lane];
    float y1 = d1 * rstd * ln_g[lane + 64] + ln_b[lane + 64];
    out[node * 128 + lane] = eluf(y0);
    out[node * 128 + 64 + lane] = eluf(y1);
  } else {
    int col = lane & 31;
    float o0 = acc0 / (ssum[0] + 1e-16f) + bias[col];
    float red = o0;
#pragma unroll
    for (int m = 1; m < 64; m <<= 1) red += __shfl_xor(red, m);
    float mu = red * (1.f / 64.f);
    float d0 = o0 - mu;
    float sq = d0 * d0;
#pragma unroll
    for (int m = 1; m < 64; m <<= 1) sq += __shfl_xor(sq, m);
    float rstd = rsqrtf(sq * (1.f / 64.f) + 1e-5f);
    float y0 = d0 * rstd * ln_g[col] + ln_b[col];
    if (lane < 32) out[node * 32 + col] = eluf(y0);
  }
}

__device__ __forceinline__ int lower_bound_dev(const int* a, int n, int key) {
  int lo = 0, hi = n;
  while (lo < hi) { int mid = (lo + hi) >> 1; if (a[mid] < key) lo = mid + 1; else hi = mid; }
  return lo;
}

__global__ __launch_bounds__(256) void pool_kernel(const float* __restrict__ x2,
                                                   const int* __restrict__ batch,
                                                   float* __restrict__ hg, int n) {
  int g = blockIdx.x;
  int lo = lower_bound_dev(batch, n, g);
  int hi = lower_bound_dev(batch, n, g + 1);
  int t = threadIdx.x;
  int c = t & 31, r = t >> 5;
  float acc = 0.f;
  for (int i = lo + r; i < hi; i += 8) acc += x2[i * 32 + c];
  __shared__ float red[8][32];
  red[r][c] = acc;
  __syncthreads();
  if (r == 0) {
    float s = 0.f;
#pragma unroll
    for (int k = 0; k < 8; ++k) s += red[k][c];
    float cnt = (float)(hi - lo);
    hg[g * 32 + c] = s / fmaxf(cnt, 1.f);
  }
}

__global__ void fc_kernel(const float* __restrict__ hg,
                          const float* __restrict__ fc1w, const float* __restrict__ fc1b,
                          const float* __restrict__ fc2w, const float* __restrict__ fc2b,
                          float* __restrict__ out) {
  int g = threadIdx.x;
  if (g >= NG) return;
  float v[32];
#pragma unroll
  for (int k = 0; k < 32; ++k) v[k] = hg[g * 32 + k];
  float z[16];
#pragma unroll
  for (int j = 0; j < 16; ++j) {
    float a = fc1b[j];
#pragma unroll
    for (int k = 0; k < 32; ++k) a = fmaf(v[k], fc1w[k * 16 + j], a);
    z[j] = fmaxf(a, 0.f);
  }
#pragma unroll
  for (int o = 0; o < 2; ++o) {
    float a = fc2b[o];
#pragma unroll
    for (int j = 0; j < 16; ++j) a = fmaf(z[j], fc2w[j * 2 + o], a);
    out[g * 2 + o] = a;
  }
}

extern "C" void kernel_launch(void* const* d_in, const int* in_sizes, int n_in,
                              void* d_out, int out_size, void* d_ws, size_t ws_size,
                              hipStream_t stream) {
  const float* x    = (const float*)d_in[0];
  const int*   ei   = (const int*)d_in[1];
  const int*   batch= (const int*)d_in[2];
  const float* W0   = (const float*)d_in[3];
  const float* as0  = (const float*)d_in[4];
  const float* ad0  = (const float*)d_in[5];
  const float* b0   = (const float*)d_in[6];
  const float* ln0g = (const float*)d_in[7];
  const float* ln0b = (const float*)d_in[8];
  const float* W1   = (const float*)d_in[9];
  const float* as1  = (const float*)d_in[10];
  const float* ad1  = (const float*)d_in[11];
  const float* b1   = (const float*)d_in[12];
  const float* ln1g = (const float*)d_in[13];
  const float* ln1b = (const float*)d_in[14];
  const float* W2   = (const float*)d_in[15];
  const float* as2  = (const float*)d_in[16];
  const float* ad2  = (const float*)d_in[17];
  const float* b2   = (const float*)d_in[18];
  const float* ln2g = (const float*)d_in[19];
  const float* ln2b = (const float*)d_in[20];
  const float* fc1w = (const float*)d_in[21];
  const float* fc1b = (const float*)d_in[22];
  const float* fc2w = (const float*)d_in[23];
  const float* fc2b = (const float*)d_in[24];
  float* out = (float*)d_out;

  const int* srce = ei;
  const int* dste = ei + EE;

  float* B1  = (float*)d_ws;                 // N*128
  float* B2  = B1 + (size_t)NN * 128;        // N*128
  float* als = B2 + (size_t)NN * 128;        // N*4
  float* ald = als + (size_t)NN * 4;         // N*4
  float* h2  = ald + (size_t)NN * 4;         // N*32
  float* x2  = h2 + (size_t)NN * 32;         // N*32
  float* hg  = x2 + (size_t)NN * 32;         // 64*32
  int* deg      = (int*)(hg + NG * 32);      // N
  int* row_ptr  = deg + NN;                  // N+1
  int* cursor   = row_ptr + NN + 1;          // N
  int* csr_src  = cursor + NN;               // E
  int* bsum     = csr_src + EE;              // SCAN_BLOCKS
  int* boff     = bsum + SCAN_BLOCKS;        // SCAN_BLOCKS

  // CSR build (shared by all 3 layers)
  zero_int_kernel<<<(NN + 255) / 256, 256, 0, stream>>>(deg, NN);
  count_deg_kernel<<<(EE + 255) / 256, 256, 0, stream>>>(dste, deg, EE);
  scanA_kernel<<<SCAN_BLOCKS, 1024, 0, stream>>>(deg, row_ptr, bsum, NN);
  scanB_kernel<<<1, 64, 0, stream>>>(bsum, boff, SCAN_BLOCKS);
  scanC_kernel<<<SCAN_BLOCKS, 1024, 0, stream>>>(row_ptr, boff, cursor, NN);
  scatter_kernel<<<(EE + 255) / 256, 256, 0, stream>>>(srce, dste, cursor, csr_src, EE);

  // layer 0
  gemm_al_kernel<128><<<625, 256, 0, stream>>>(x, W0, as0, ad0, B1, als, ald);
  aggregate_kernel<4, 32><<<(NN + 3) / 4, 256, 0, stream>>>(B1, als, ald, row_ptr, csr_src,
                                                            b0, ln0g, ln0b, B2, NN);
  // layer 1
  gemm_al_kernel<128><<<625, 256, 0, stream>>>(B2, W1, as1, ad1, B1, als, ald);
  aggregate_kernel<4, 32><<<(NN + 3) / 4, 256, 0, stream>>>(B1, als, ald, row_ptr, csr_src,
                                                            b1, ln1g, ln1b, B2, NN);
  // layer 2
  gemm_al_kernel<32><<<625, 256, 0, stream>>>(B2, W2, as2, ad2, h2, als, ald);
  aggregate_kernel<1, 32><<<(NN + 3) / 4, 256, 0, stream>>>(h2, als, ald, row_ptr, csr_src,
                                                            b2, ln2g, ln2b, x2, NN);
  // pool + classifier
  pool_kernel<<<NG, 256, 0, stream>>>(x2, batch, hg, NN);
  fc_kernel<<<1, 64, 0, stream>>>(hg, fc1w, fc1b, fc2w, fc2b, out);
}

// Round 4
// 304.491 us; speedup vs baseline: 2.4490x; 1.0614x over previous
//
#include <hip/hip_runtime.h>
#include <math.h>

#define NN 40000
#define EE 640000
#define NG 64
#define SCAN_BLOCKS ((NN + 1023) / 1024)

__device__ __forceinline__ float eluf(float x) { return x > 0.f ? x : expm1f(x); }

typedef const __attribute__((address_space(1))) char gas_char;
typedef __attribute__((address_space(3))) char las_char;

__device__ __forceinline__ void async_copy16(void* l, const void* g) {
  __builtin_amdgcn_global_load_lds((gas_char*)g, (las_char*)l, 16, 0, 0);
}

__device__ __forceinline__ unsigned f2bf(float x) {  // RNE f32->bf16 (no NaN inputs)
  unsigned u = __float_as_uint(x);
  return (u + 0x7fffu + ((u >> 16) & 1u)) >> 16;
}
__device__ __forceinline__ unsigned packbf(float lo, float hi) {
  return f2bf(lo) | (f2bf(hi) << 16);
}
__device__ __forceinline__ float bflo(unsigned p) { return __uint_as_float(p << 16); }
__device__ __forceinline__ float bfhi(unsigned p) { return __uint_as_float(p & 0xffff0000u); }

__global__ void zero_int_kernel(int* __restrict__ p, int n) {
  int i = blockIdx.x * 256 + threadIdx.x;
  if (i < n) p[i] = 0;
}

__global__ void count_deg_kernel(const int* __restrict__ dst, int* __restrict__ deg, int e) {
  int i = blockIdx.x * 256 + threadIdx.x;
  if (i < e) atomicAdd(&deg[dst[i]], 1);
}

__global__ __launch_bounds__(1024) void scanA_kernel(const int* __restrict__ deg,
                                                     int* __restrict__ row_ptr,
                                                     int* __restrict__ bsum, int n) {
  __shared__ int wsum[16];
  int t = threadIdx.x, lane = t & 63, wid = t >> 6;
  int i = blockIdx.x * 1024 + t;
  int v = (i < n) ? deg[i] : 0;
#pragma unroll
  for (int off = 1; off < 64; off <<= 1) {
    int u = __shfl_up(v, off);
    if (lane >= off) v += u;
  }
  if (lane == 63) wsum[wid] = v;
  __syncthreads();
  if (t < 16) {
    int w = wsum[t];
#pragma unroll
    for (int off = 1; off < 16; off <<= 1) {
      int u = __shfl_up(w, off);
      if (t >= off) w += u;
    }
    wsum[t] = w;
  }
  __syncthreads();
  if (wid > 0) v += wsum[wid - 1];
  if (i < n) row_ptr[i + 1] = v;
  if (t == 1023) bsum[blockIdx.x] = v;
}

__global__ void scanB_kernel(const int* __restrict__ bsum, int* __restrict__ boff, int nb) {
  int lane = threadIdx.x;
  int v = (lane < nb) ? bsum[lane] : 0;
  int orig = v;
#pragma unroll
  for (int off = 1; off < 64; off <<= 1) {
    int u = __shfl_up(v, off);
    if (lane >= off) v += u;
  }
  if (lane < nb) boff[lane] = v - orig;
}

__global__ __launch_bounds__(1024) void scanC_kernel(int* __restrict__ row_ptr,
                                                     const int* __restrict__ boff,
                                                     int* __restrict__ cursor, int n) {
  int i = blockIdx.x * 1024 + threadIdx.x;
  if (i < n) {
    int v = row_ptr[i + 1] + boff[i >> 10];
    row_ptr[i + 1] = v;
    if (i + 1 < n) cursor[i + 1] = v;
    if (i == 0) { cursor[0] = 0; row_ptr[0] = 0; }
  }
}

__global__ void scatter_kernel(const int* __restrict__ src, const int* __restrict__ dst,
                               int* __restrict__ cursor, int* __restrict__ csr_src, int e) {
  int i = blockIdx.x * 256 + threadIdx.x;
  if (i < e) {
    int d = dst[i];
    int pos = atomicAdd(&cursor[d], 1);
    csr_src[pos] = src[i];
  }
}

// GEMM (K=128, OUT=128): h = x @ W written as PACKED BF16 pairs
// hb[row*64 + j] = (bf16(h[row][j]), bf16(h[row][j+64])), plus fused als/ald.
// Thread (cg=t&31, rg=t>>5) owns rows rg*8..+8, cols {2cg, 2cg+1, 2cg+64, 2cg+65}.
__global__ __launch_bounds__(256, 2) void gemm128_kernel(
    const float* __restrict__ x, const float* __restrict__ W,
    const float* __restrict__ a_s, const float* __restrict__ a_d,
    unsigned* __restrict__ hb, float* __restrict__ als, float* __restrict__ ald)
{
  __shared__ float xs[64 * 128];
  __shared__ float ws[2][32 * 128];

  int t = threadIdx.x;
  int row0 = blockIdx.x * 64;

  {
    const char* xg = (const char*)(x + (size_t)row0 * 128);
    char* xl = (char*)xs;
#pragma unroll
    for (int it = 0; it < 8; ++it)
      async_copy16(xl + it * 4096 + t * 16, xg + it * 4096 + t * 16);
  }
  {
    const char* wg = (const char*)W;
    char* wl = (char*)ws[0];
#pragma unroll
    for (int p = 0; p < 4; ++p)
      async_copy16(wl + p * 4096 + t * 16, wg + p * 4096 + t * 16);
  }
  __syncthreads();

  int cg = t & 31, rg = t >> 5;
  int r0 = rg * 8;
  int jlo = 2 * cg;

  float acc[8][4];
#pragma unroll
  for (int r = 0; r < 8; ++r)
#pragma unroll
    for (int c = 0; c < 4; ++c) acc[r][c] = 0.f;

  for (int ch = 0; ch < 4; ++ch) {
    if (ch < 3) {
      const char* wg = (const char*)W + (size_t)(ch + 1) * 32 * 128 * 4;
      char* wl = (char*)ws[(ch + 1) & 1];
#pragma unroll
      for (int p = 0; p < 4; ++p)
        async_copy16(wl + p * 4096 + t * 16, wg + p * 4096 + t * 16);
    }
    const float* wc = ws[ch & 1];
    const float* xc = xs + ch * 32;
#pragma unroll
    for (int kk = 0; kk < 32; kk += 4) {
      float2 wlo[4], whi[4];
#pragma unroll
      for (int q = 0; q < 4; ++q) {
        wlo[q] = *reinterpret_cast<const float2*>(&wc[(kk + q) * 128 + jlo]);
        whi[q] = *reinterpret_cast<const float2*>(&wc[(kk + q) * 128 + 64 + jlo]);
      }
#pragma unroll
      for (int r = 0; r < 8; ++r) {
        float4 xv = *reinterpret_cast<const float4*>(&xc[(r0 + r) * 128 + kk]);
        float a0 = acc[r][0], a1 = acc[r][1], a2 = acc[r][2], a3 = acc[r][3];
        a0 = fmaf(xv.x, wlo[0].x, a0); a1 = fmaf(xv.x, wlo[0].y, a1);
        a2 = fmaf(xv.x, whi[0].x, a2); a3 = fmaf(xv.x, whi[0].y, a3);
        a0 = fmaf(xv.y, wlo[1].x, a0); a1 = fmaf(xv.y, wlo[1].y, a1);
        a2 = fmaf(xv.y, whi[1].x, a2); a3 = fmaf(xv.y, whi[1].y, a3);
        a0 = fmaf(xv.z, wlo[2].x, a0); a1 = fmaf(xv.z, wlo[2].y, a1);
        a2 = fmaf(xv.z, whi[2].x, a2); a3 = fmaf(xv.z, whi[2].y, a3);
        a0 = fmaf(xv.w, wlo[3].x, a0); a1 = fmaf(xv.w, wlo[3].y, a1);
        a2 = fmaf(xv.w, whi[3].x, a2); a3 = fmaf(xv.w, whi[3].y, a3);
        acc[r][0] = a0; acc[r][1] = a1; acc[r][2] = a2; acc[r][3] = a3;
      }
    }
    __syncthreads();
  }

  // packed bf16 h write: j=jlo packs (col jlo, col jlo+64); j=jlo+1 likewise
#pragma unroll
  for (int r = 0; r < 8; ++r) {
    uint2 pv;
    pv.x = packbf(acc[r][0], acc[r][2]);
    pv.y = packbf(acc[r][1], acc[r][3]);
    *reinterpret_cast<uint2*>(&hb[(size_t)(row0 + r0 + r) * 64 + jlo]) = pv;
  }

  // attention projections: this thread covers heads hA = cg>>4 and hA+2
  float as0 = a_s[jlo], as1 = a_s[jlo + 1], as2 = a_s[jlo + 64], as3 = a_s[jlo + 65];
  float ad0 = a_d[jlo], ad1 = a_d[jlo + 1], ad2 = a_d[jlo + 64], ad3 = a_d[jlo + 65];
  int lane = t & 63;
#pragma unroll
  for (int r = 0; r < 8; ++r) {
    float psa = fmaf(acc[r][0], as0, acc[r][1] * as1);
    float psb = fmaf(acc[r][2], as2, acc[r][3] * as3);
    float pda = fmaf(acc[r][0], ad0, acc[r][1] * ad1);
    float pdb = fmaf(acc[r][2], ad2, acc[r][3] * ad3);
#pragma unroll
    for (int m = 1; m < 16; m <<= 1) {
      psa += __shfl_xor(psa, m); psb += __shfl_xor(psb, m);
      pda += __shfl_xor(pda, m); pdb += __shfl_xor(pdb, m);
    }
    if ((lane & 15) == 0) {
      int hA = (lane >> 4) & 1;
      size_t row = (size_t)(row0 + r0 + r);
      als[row * 4 + hA] = psa; als[row * 4 + hA + 2] = psb;
      ald[row * 4 + hA] = pda; ald[row * 4 + hA + 2] = pdb;
    }
  }
}

// GEMM (K=128, OUT=32) f32 out, fused single-head als/ald.
__global__ __launch_bounds__(256, 2) void gemm32_kernel(
    const float* __restrict__ x, const float* __restrict__ W,
    const float* __restrict__ a_s, const float* __restrict__ a_d,
    float* __restrict__ h, float* __restrict__ als, float* __restrict__ ald)
{
  __shared__ float xs[64 * 128];
  __shared__ float ws[2][32 * 32];
  int t = threadIdx.x;
  int row0 = blockIdx.x * 64;
  {
    const char* xg = (const char*)(x + (size_t)row0 * 128);
    char* xl = (char*)xs;
#pragma unroll
    for (int it = 0; it < 8; ++it)
      async_copy16(xl + it * 4096 + t * 16, xg + it * 4096 + t * 16);
  }
  async_copy16((char*)ws[0] + t * 16, (const char*)W + t * 16);
  __syncthreads();

  int cg = t & 7, rg = t >> 3;
  int r0 = rg * 2, c0 = cg * 4;
  float acc[2][4];
#pragma unroll
  for (int r = 0; r < 2; ++r)
#pragma unroll
    for (int c = 0; c < 4; ++c) acc[r][c] = 0.f;

  for (int ch = 0; ch < 4; ++ch) {
    if (ch < 3) {
      const char* wg = (const char*)W + (size_t)(ch + 1) * 32 * 32 * 4;
      async_copy16((char*)ws[(ch + 1) & 1] + t * 16, wg + t * 16);
    }
    const float* wc = ws[ch & 1];
    const float* xc = xs + ch * 32;
#pragma unroll
    for (int kk = 0; kk < 32; kk += 4) {
      float4 wv[4];
#pragma unroll
      for (int q = 0; q < 4; ++q)
        wv[q] = *reinterpret_cast<const float4*>(&wc[(kk + q) * 32 + c0]);
#pragma unroll
      for (int r = 0; r < 2; ++r) {
        float4 xv = *reinterpret_cast<const float4*>(&xc[(r0 + r) * 128 + kk]);
#pragma unroll
        for (int c = 0; c < 4; ++c) {
          float a = acc[r][c];
          a = fmaf(xv.x, (&wv[0].x)[c], a);
          a = fmaf(xv.y, (&wv[1].x)[c], a);
          a = fmaf(xv.z, (&wv[2].x)[c], a);
          a = fmaf(xv.w, (&wv[3].x)[c], a);
          acc[r][c] = a;
        }
      }
    }
    __syncthreads();
  }

#pragma unroll
  for (int r = 0; r < 2; ++r) {
    float4 hv = make_float4(acc[r][0], acc[r][1], acc[r][2], acc[r][3]);
    *reinterpret_cast<float4*>(&h[(size_t)(row0 + r0 + r) * 32 + c0]) = hv;
  }
  float asv[4], adv[4];
#pragma unroll
  for (int c = 0; c < 4; ++c) { asv[c] = a_s[c0 + c]; adv[c] = a_d[c0 + c]; }
#pragma unroll
  for (int r = 0; r < 2; ++r) {
    float ps = acc[r][0] * asv[0] + acc[r][1] * asv[1] + acc[r][2] * asv[2] + acc[r][3] * asv[3];
    float pd = acc[r][0] * adv[0] + acc[r][1] * adv[1] + acc[r][2] * adv[2] + acc[r][3] * adv[3];
#pragma unroll
    for (int m = 1; m < 8; m <<= 1) { ps += __shfl_xor(ps, m); pd += __shfl_xor(pd, m); }
    if ((t & 7) == 0) {
      als[row0 + r0 + r] = ps;
      ald[row0 + r0 + r] = pd;
    }
  }
}

// Aggregate for OUT=128 (4 heads x 32), packed-bf16 h gather.
// One wave per dst node; single-pass softmax when deg<=64 (always, in practice).
__global__ __launch_bounds__(256) void aggregate128_kernel(
    const unsigned* __restrict__ hb, const float* __restrict__ als, const float* __restrict__ ald,
    const int* __restrict__ row_ptr, const int* __restrict__ csr_src,
    const float* __restrict__ bias, const float* __restrict__ ln_g, const float* __restrict__ ln_b,
    float* __restrict__ out, int n)
{
  __shared__ int s_src[4][64];
  __shared__ float s_ex[4][64][4];
  int t = threadIdx.x, lane = t & 63, wid = t >> 6;
  int node = blockIdx.x * 4 + wid;
  if (node >= n) return;
  int start = row_ptr[node], end = row_ptr[node + 1];
  int deg = end - start;

  float4 adq = reinterpret_cast<const float4*>(ald)[node];
  float adl[4] = {adq.x, adq.y, adq.z, adq.w};
  int h0 = lane >> 5, h1 = h0 + 2;
  float acc0 = 0.f, acc1 = 0.f;
  float ssum[4];

  if (deg <= 64) {
    bool valid = lane < deg;
    int s = 0;
    if (valid) s = csr_src[start + lane];
    float4 q = reinterpret_cast<const float4*>(als)[s];
    float v[4] = {q.x, q.y, q.z, q.w};
    float mx[4];
#pragma unroll
    for (int hh = 0; hh < 4; ++hh) {
      float w = v[hh] + adl[hh];
      w = w > 0.f ? w : 0.2f * w;
      v[hh] = valid ? w : -INFINITY;
      mx[hh] = v[hh];
    }
#pragma unroll
    for (int hh = 0; hh < 4; ++hh)
#pragma unroll
      for (int m = 1; m < 64; m <<= 1) mx[hh] = fmaxf(mx[hh], __shfl_xor(mx[hh], m));
    float ex[4];
#pragma unroll
    for (int hh = 0; hh < 4; ++hh) {
      ex[hh] = valid ? __expf(v[hh] - mx[hh]) : 0.f;
      ssum[hh] = ex[hh];
    }
#pragma unroll
    for (int hh = 0; hh < 4; ++hh)
#pragma unroll
      for (int m = 1; m < 64; m <<= 1) ssum[hh] += __shfl_xor(ssum[hh], m);

    s_src[wid][lane] = s;
#pragma unroll
    for (int hh = 0; hh < 4; ++hh) s_ex[wid][lane][hh] = ex[hh];

    int j = 0;
    for (; j + 2 <= deg; j += 2) {
      int sa = s_src[wid][j], sb = s_src[wid][j + 1];
      unsigned ua = hb[(size_t)sa * 64 + lane];
      unsigned ub = hb[(size_t)sb * 64 + lane];
      float wa0 = s_ex[wid][j][h0], wa1 = s_ex[wid][j][h1];
      float wb0 = s_ex[wid][j + 1][h0], wb1 = s_ex[wid][j + 1][h1];
      acc0 = fmaf(wa0, bflo(ua), acc0); acc1 = fmaf(wa1, bfhi(ua), acc1);
      acc0 = fmaf(wb0, bflo(ub), acc0); acc1 = fmaf(wb1, bfhi(ub), acc1);
    }
    if (j < deg) {
      int sa = s_src[wid][j];
      unsigned ua = hb[(size_t)sa * 64 + lane];
      acc0 = fmaf(s_ex[wid][j][h0], bflo(ua), acc0);
      acc1 = fmaf(s_ex[wid][j][h1], bfhi(ua), acc1);
    }
  } else {
    // generic 2-pass fallback (deg > 64: essentially never at avg degree 16)
    float mx[4];
#pragma unroll
    for (int hh = 0; hh < 4; ++hh) mx[hh] = -INFINITY;
    for (int eb = start; eb < end; eb += 64) {
      int e = eb + lane;
      if (e < end) {
        int s = csr_src[e];
        float4 q = reinterpret_cast<const float4*>(als)[s];
        float av[4] = {q.x, q.y, q.z, q.w};
#pragma unroll
        for (int hh = 0; hh < 4; ++hh) {
          float v = av[hh] + adl[hh];
          v = v > 0.f ? v : 0.2f * v;
          mx[hh] = fmaxf(mx[hh], v);
        }
      }
    }
#pragma unroll
    for (int hh = 0; hh < 4; ++hh)
#pragma unroll
      for (int m = 1; m < 64; m <<= 1) mx[hh] = fmaxf(mx[hh], __shfl_xor(mx[hh], m));
#pragma unroll
    for (int hh = 0; hh < 4; ++hh) ssum[hh] = 0.f;
    for (int eb = start; eb < end; eb += 64) {
      int e = eb + lane;
      int s = 0;
      float exv[4] = {0.f, 0.f, 0.f, 0.f};
      if (e < end) {
        s = csr_src[e];
        float4 q = reinterpret_cast<const float4*>(als)[s];
        float av[4] = {q.x, q.y, q.z, q.w};
#pragma unroll
        for (int hh = 0; hh < 4; ++hh) {
          float v = av[hh] + adl[hh];
          v = v > 0.f ? v : 0.2f * v;
          exv[hh] = __expf(v - mx[hh]);
          ssum[hh] += exv[hh];
        }
      }
      s_src[wid][lane] = s;
#pragma unroll
      for (int hh = 0; hh < 4; ++hh) s_ex[wid][lane][hh] = exv[hh];
      int cnt = end - eb; if (cnt > 64) cnt = 64;
      for (int j = 0; j < cnt; ++j) {
        int sj = s_src[wid][j];
        unsigned u = hb[(size_t)sj * 64 + lane];
        acc0 = fmaf(s_ex[wid][j][h0], bflo(u), acc0);
        acc1 = fmaf(s_ex[wid][j][h1], bfhi(u), acc1);
      }
    }
#pragma unroll
    for (int hh = 0; hh < 4; ++hh)
#pragma unroll
      for (int m = 1; m < 64; m <<= 1) ssum[hh] += __shfl_xor(ssum[hh], m);
  }

  float o0 = acc0 / (ssum[h0] + 1e-16f) + bias[lane];
  float o1 = acc1 / (ssum[h1] + 1e-16f) + bias[lane + 64];
  float red = o0 + o1;
#pragma unroll
  for (int m = 1; m < 64; m <<= 1) red += __shfl_xor(red, m);
  float mu = red * (1.f / 128.f);
  float d0 = o0 - mu, d1 = o1 - mu;
  float sq = d0 * d0 + d1 * d1;
#pragma unroll
  for (int m = 1; m < 64; m <<= 1) sq += __shfl_xor(sq, m);
  float rstd = rsqrtf(sq * (1.f / 128.f) + 1e-5f);
  float y0 = d0 * rstd * ln_g[lane] + ln_b[lane];
  float y1 = d1 * rstd * ln_g[lane + 64] + ln_b[lane + 64];
  out[(size_t)node * 128 + lane] = eluf(y0);
  out[(size_t)node * 128 + 64 + lane] = eluf(y1);
}

// Aggregate for OUT=32 single head (f32 h rows), fused bias+LN+ELU.
__global__ __launch_bounds__(256) void aggregate32_kernel(
    const float* __restrict__ h, const float* __restrict__ als, const float* __restrict__ ald,
    const int* __restrict__ row_ptr, const int* __restrict__ csr_src,
    const float* __restrict__ bias, const float* __restrict__ ln_g, const float* __restrict__ ln_b,
    float* __restrict__ out, int n)
{
  __shared__ int s_src[4][64];
  __shared__ float s_ex[4][64];
  int t = threadIdx.x, lane = t & 63, wid = t >> 6;
  int node = blockIdx.x * 4 + wid;
  if (node >= n) return;
  int start = row_ptr[node], end = row_ptr[node + 1];
  int deg = end - start;
  float adl = ald[node];
  int col = lane & 31;
  float acc0 = 0.f, ssum = 0.f;

  if (deg <= 64) {
    bool valid = lane < deg;
    int s = 0;
    if (valid) s = csr_src[start + lane];
    float v = als[s] + adl;
    v = v > 0.f ? v : 0.2f * v;
    v = valid ? v : -INFINITY;
    float mx = v;
#pragma unroll
    for (int m = 1; m < 64; m <<= 1) mx = fmaxf(mx, __shfl_xor(mx, m));
    float ex = valid ? __expf(v - mx) : 0.f;
    ssum = ex;
#pragma unroll
    for (int m = 1; m < 64; m <<= 1) ssum += __shfl_xor(ssum, m);
    s_src[wid][lane] = s;
    s_ex[wid][lane] = ex;
    int j = 0;
    for (; j + 2 <= deg; j += 2) {
      int sa = s_src[wid][j], sb = s_src[wid][j + 1];
      float ha = h[(size_t)sa * 32 + col];
      float hbv = h[(size_t)sb * 32 + col];
      acc0 = fmaf(s_ex[wid][j], ha, acc0);
      acc0 = fmaf(s_ex[wid][j + 1], hbv, acc0);
    }
    if (j < deg) acc0 = fmaf(s_ex[wid][j], h[(size_t)s_src[wid][j] * 32 + col], acc0);
  } else {
    float mx = -INFINITY;
    for (int eb = start; eb < end; eb += 64) {
      int e = eb + lane;
      if (e < end) {
        float v = als[csr_src[e]] + adl;
        v = v > 0.f ? v : 0.2f * v;
        mx = fmaxf(mx, v);
      }
    }
#pragma unroll
    for (int m = 1; m < 64; m <<= 1) mx = fmaxf(mx, __shfl_xor(mx, m));
    for (int eb = start; eb < end; eb += 64) {
      int e = eb + lane;
      int s = 0; float ex = 0.f;
      if (e < end) {
        s = csr_src[e];
        float v = als[s] + adl;
        v = v > 0.f ? v : 0.2f * v;
        ex = __expf(v - mx);
        ssum += ex;
      }
      s_src[wid][lane] = s;
      s_ex[wid][lane] = ex;
      int cnt = end - eb; if (cnt > 64) cnt = 64;
      for (int j = 0; j < cnt; ++j)
        acc0 = fmaf(s_ex[wid][j], h[(size_t)s_src[wid][j] * 32 + col], acc0);
    }
#pragma unroll
    for (int m = 1; m < 64; m <<= 1) ssum += __shfl_xor(ssum, m);
  }

  float o0 = acc0 / (ssum + 1e-16f) + bias[col];
  float red = o0;
#pragma unroll
  for (int m = 1; m < 64; m <<= 1) red += __shfl_xor(red, m);
  float mu = red * (1.f / 64.f);
  float d0 = o0 - mu;
  float sq = d0 * d0;
#pragma unroll
  for (int m = 1; m < 64; m <<= 1) sq += __shfl_xor(sq, m);
  float rstd = rsqrtf(sq * (1.f / 64.f) + 1e-5f);
  float y0 = d0 * rstd * ln_g[col] + ln_b[col];
  if (lane < 32) out[(size_t)node * 32 + col] = eluf(y0);
}

__device__ __forceinline__ int lower_bound_dev(const int* a, int n, int key) {
  int lo = 0, hi = n;
  while (lo < hi) { int mid = (lo + hi) >> 1; if (a[mid] < key) lo = mid + 1; else hi = mid; }
  return lo;
}

__global__ __launch_bounds__(256) void pool_kernel(const float* __restrict__ x2,
                                                   const int* __restrict__ batch,
                                                   float* __restrict__ hg, int n) {
  int g = blockIdx.x;
  int lo = lower_bound_dev(batch, n, g);
  int hi = lower_bound_dev(batch, n, g + 1);
  int t = threadIdx.x;
  int c = t & 31, r = t >> 5;
  float acc = 0.f;
  for (int i = lo + r; i < hi; i += 8) acc += x2[(size_t)i * 32 + c];
  __shared__ float red[8][32];
  red[r][c] = acc;
  __syncthreads();
  if (r == 0) {
    float s = 0.f;
#pragma unroll
    for (int k = 0; k < 8; ++k) s += red[k][c];
    float cnt = (float)(hi - lo);
    hg[g * 32 + c] = s / fmaxf(cnt, 1.f);
  }
}

__global__ void fc_kernel(const float* __restrict__ hg,
                          const float* __restrict__ fc1w, const float* __restrict__ fc1b,
                          const float* __restrict__ fc2w, const float* __restrict__ fc2b,
                          float* __restrict__ out) {
  int g = threadIdx.x;
  if (g >= NG) return;
  float v[32];
#pragma unroll
  for (int k = 0; k < 32; ++k) v[k] = hg[g * 32 + k];
  float z[16];
#pragma unroll
  for (int j = 0; j < 16; ++j) {
    float a = fc1b[j];
#pragma unroll
    for (int k = 0; k < 32; ++k) a = fmaf(v[k], fc1w[k * 16 + j], a);
    z[j] = fmaxf(a, 0.f);
  }
#pragma unroll
  for (int o = 0; o < 2; ++o) {
    float a = fc2b[o];
#pragma unroll
    for (int j = 0; j < 16; ++j) a = fmaf(z[j], fc2w[j * 2 + o], a);
    out[g * 2 + o] = a;
  }
}

extern "C" void kernel_launch(void* const* d_in, const int* in_sizes, int n_in,
                              void* d_out, int out_size, void* d_ws, size_t ws_size,
                              hipStream_t stream) {
  const float* x    = (const float*)d_in[0];
  const int*   ei   = (const int*)d_in[1];
  const int*   batch= (const int*)d_in[2];
  const float* W0   = (const float*)d_in[3];
  const float* as0  = (const float*)d_in[4];
  const float* ad0  = (const float*)d_in[5];
  const float* b0   = (const float*)d_in[6];
  const float* ln0g = (const float*)d_in[7];
  const float* ln0b = (const float*)d_in[8];
  const float* W1   = (const float*)d_in[9];
  const float* as1  = (const float*)d_in[10];
  const float* ad1  = (const float*)d_in[11];
  const float* b1   = (const float*)d_in[12];
  const float* ln1g = (const float*)d_in[13];
  const float* ln1b = (const float*)d_in[14];
  const float* W2   = (const float*)d_in[15];
  const float* as2  = (const float*)d_in[16];
  const float* ad2  = (const float*)d_in[17];
  const float* b2   = (const float*)d_in[18];
  const float* ln2g = (const float*)d_in[19];
  const float* ln2b = (const float*)d_in[20];
  const float* fc1w = (const float*)d_in[21];
  const float* fc1b = (const float*)d_in[22];
  const float* fc2w = (const float*)d_in[23];
  const float* fc2b = (const float*)d_in[24];
  float* out = (float*)d_out;

  const int* srce = ei;
  const int* dste = ei + EE;

  unsigned* hb = (unsigned*)d_ws;            // N*64 packed bf16 pairs
  float* B2  = (float*)(hb + (size_t)NN * 64); // N*128
  float* als = B2 + (size_t)NN * 128;        // N*4
  float* ald = als + (size_t)NN * 4;         // N*4
  float* h2  = ald + (size_t)NN * 4;         // N*32
  float* x2  = h2 + (size_t)NN * 32;         // N*32
  float* hg  = x2 + (size_t)NN * 32;         // 64*32
  int* deg      = (int*)(hg + NG * 32);      // N
  int* row_ptr  = deg + NN;                  // N+1
  int* cursor   = row_ptr + NN + 1;          // N
  int* csr_src  = cursor + NN;               // E
  int* bsum     = csr_src + EE;              // SCAN_BLOCKS
  int* boff     = bsum + SCAN_BLOCKS;        // SCAN_BLOCKS

  // CSR build (shared by all 3 layers)
  zero_int_kernel<<<(NN + 255) / 256, 256, 0, stream>>>(deg, NN);
  count_deg_kernel<<<(EE + 255) / 256, 256, 0, stream>>>(dste, deg, EE);
  scanA_kernel<<<SCAN_BLOCKS, 1024, 0, stream>>>(deg, row_ptr, bsum, NN);
  scanB_kernel<<<1, 64, 0, stream>>>(bsum, boff, SCAN_BLOCKS);
  scanC_kernel<<<SCAN_BLOCKS, 1024, 0, stream>>>(row_ptr, boff, cursor, NN);
  scatter_kernel<<<(EE + 255) / 256, 256, 0, stream>>>(srce, dste, cursor, csr_src, EE);

  // layer 0
  gemm128_kernel<<<625, 256, 0, stream>>>(x, W0, as0, ad0, hb, als, ald);
  aggregate128_kernel<<<(NN + 3) / 4, 256, 0, stream>>>(hb, als, ald, row_ptr, csr_src,
                                                        b0, ln0g, ln0b, B2, NN);
  // layer 1
  gemm128_kernel<<<625, 256, 0, stream>>>(B2, W1, as1, ad1, hb, als, ald);
  aggregate128_kernel<<<(NN + 3) / 4, 256, 0, stream>>>(hb, als, ald, row_ptr, csr_src,
                                                        b1, ln1g, ln1b, B2, NN);
  // layer 2
  gemm32_kernel<<<625, 256, 0, stream>>>(B2, W2, as2, ad2, h2, als, ald);
  aggregate32_kernel<<<(NN + 3) / 4, 256, 0, stream>>>(h2, als, ald, row_ptr, csr_src,
                                                       b2, ln2g, ln2b, x2, NN);
  // pool + classifier
  pool_kernel<<<NG, 256, 0, stream>>>(x2, batch, hg, NN);
  fc_kernel<<<1, 64, 0, stream>>>(hg, fc1w, fc1b, fc2w, fc2b, out);
}

// Round 5
// 283.648 us; speedup vs baseline: 2.6289x; 1.0735x over previous
//
#include <hip/hip_runtime.h>
#include <math.h>

#define NN 40000
#define EE 640000
#define NG 64
#define SCAN_BLOCKS ((NN + 1023) / 1024)

__device__ __forceinline__ float eluf(float x) { return x > 0.f ? x : expm1f(x); }

typedef const __attribute__((address_space(1))) char gas_char;
typedef __attribute__((address_space(3))) char las_char;

__device__ __forceinline__ void async_copy16(void* l, const void* g) {
  __builtin_amdgcn_global_load_lds((gas_char*)g, (las_char*)l, 16, 0, 0);
}

__device__ __forceinline__ unsigned f2bf(float x) {  // RNE f32->bf16 (no NaN inputs)
  unsigned u = __float_as_uint(x);
  return (u + 0x7fffu + ((u >> 16) & 1u)) >> 16;
}
__device__ __forceinline__ unsigned packbf(float lo, float hi) {
  return f2bf(lo) | (f2bf(hi) << 16);
}
__device__ __forceinline__ float bflo(unsigned p) { return __uint_as_float(p << 16); }
__device__ __forceinline__ float bfhi(unsigned p) { return __uint_as_float(p & 0xffff0000u); }

__global__ void zero_int_kernel(int* __restrict__ p, int n) {
  int i = blockIdx.x * 256 + threadIdx.x;
  if (i < n) p[i] = 0;
}

__global__ void count_deg_kernel(const int* __restrict__ dst, int* __restrict__ deg, int e) {
  int i = blockIdx.x * 256 + threadIdx.x;
  if (i < e) atomicAdd(&deg[dst[i]], 1);
}

__global__ __launch_bounds__(1024) void scanA_kernel(const int* __restrict__ deg,
                                                     int* __restrict__ row_ptr,
                                                     int* __restrict__ bsum, int n) {
  __shared__ int wsum[16];
  int t = threadIdx.x, lane = t & 63, wid = t >> 6;
  int i = blockIdx.x * 1024 + t;
  int v = (i < n) ? deg[i] : 0;
#pragma unroll
  for (int off = 1; off < 64; off <<= 1) {
    int u = __shfl_up(v, off);
    if (lane >= off) v += u;
  }
  if (lane == 63) wsum[wid] = v;
  __syncthreads();
  if (t < 16) {
    int w = wsum[t];
#pragma unroll
    for (int off = 1; off < 16; off <<= 1) {
      int u = __shfl_up(w, off);
      if (t >= off) w += u;
    }
    wsum[t] = w;
  }
  __syncthreads();
  if (wid > 0) v += wsum[wid - 1];
  if (i < n) row_ptr[i + 1] = v;
  if (t == 1023) bsum[blockIdx.x] = v;
}

__global__ void scanB_kernel(const int* __restrict__ bsum, int* __restrict__ boff, int nb) {
  int lane = threadIdx.x;
  int v = (lane < nb) ? bsum[lane] : 0;
  int orig = v;
#pragma unroll
  for (int off = 1; off < 64; off <<= 1) {
    int u = __shfl_up(v, off);
    if (lane >= off) v += u;
  }
  if (lane < nb) boff[lane] = v - orig;
}

__global__ __launch_bounds__(1024) void scanC_kernel(int* __restrict__ row_ptr,
                                                     const int* __restrict__ boff,
                                                     int* __restrict__ cursor, int n) {
  int i = blockIdx.x * 1024 + threadIdx.x;
  if (i < n) {
    int v = row_ptr[i + 1] + boff[i >> 10];
    row_ptr[i + 1] = v;
    if (i + 1 < n) cursor[i + 1] = v;
    if (i == 0) { cursor[0] = 0; row_ptr[0] = 0; }
  }
}

__global__ void scatter_kernel(const int* __restrict__ src, const int* __restrict__ dst,
                               int* __restrict__ cursor, int* __restrict__ csr_src, int e) {
  int i = blockIdx.x * 256 + threadIdx.x;
  if (i < e) {
    int d = dst[i];
    int pos = atomicAdd(&cursor[d], 1);
    csr_src[pos] = src[i];
  }
}

// GEMM (K=128, OUT=128): h = x @ W written as PACKED BF16 pairs
// hb[row*64 + j] = (bf16(h[row][j]), bf16(h[row][j+64])), plus fused als/ald.
__global__ __launch_bounds__(256, 2) void gemm128_kernel(
    const float* __restrict__ x, const float* __restrict__ W,
    const float* __restrict__ a_s, const float* __restrict__ a_d,
    unsigned* __restrict__ hb, float* __restrict__ als, float* __restrict__ ald)
{
  __shared__ float xs[64 * 128];
  __shared__ float ws[2][32 * 128];

  int t = threadIdx.x;
  int row0 = blockIdx.x * 64;

  {
    const char* xg = (const char*)(x + (size_t)row0 * 128);
    char* xl = (char*)xs;
#pragma unroll
    for (int it = 0; it < 8; ++it)
      async_copy16(xl + it * 4096 + t * 16, xg + it * 4096 + t * 16);
  }
  {
    const char* wg = (const char*)W;
    char* wl = (char*)ws[0];
#pragma unroll
    for (int p = 0; p < 4; ++p)
      async_copy16(wl + p * 4096 + t * 16, wg + p * 4096 + t * 16);
  }
  __syncthreads();

  int cg = t & 31, rg = t >> 5;
  int r0 = rg * 8;
  int jlo = 2 * cg;

  float acc[8][4];
#pragma unroll
  for (int r = 0; r < 8; ++r)
#pragma unroll
    for (int c = 0; c < 4; ++c) acc[r][c] = 0.f;

  for (int ch = 0; ch < 4; ++ch) {
    if (ch < 3) {
      const char* wg = (const char*)W + (size_t)(ch + 1) * 32 * 128 * 4;
      char* wl = (char*)ws[(ch + 1) & 1];
#pragma unroll
      for (int p = 0; p < 4; ++p)
        async_copy16(wl + p * 4096 + t * 16, wg + p * 4096 + t * 16);
    }
    const float* wc = ws[ch & 1];
    const float* xc = xs + ch * 32;
#pragma unroll
    for (int kk = 0; kk < 32; kk += 4) {
      float2 wlo[4], whi[4];
#pragma unroll
      for (int q = 0; q < 4; ++q) {
        wlo[q] = *reinterpret_cast<const float2*>(&wc[(kk + q) * 128 + jlo]);
        whi[q] = *reinterpret_cast<const float2*>(&wc[(kk + q) * 128 + 64 + jlo]);
      }
#pragma unroll
      for (int r = 0; r < 8; ++r) {
        float4 xv = *reinterpret_cast<const float4*>(&xc[(r0 + r) * 128 + kk]);
        float a0 = acc[r][0], a1 = acc[r][1], a2 = acc[r][2], a3 = acc[r][3];
        a0 = fmaf(xv.x, wlo[0].x, a0); a1 = fmaf(xv.x, wlo[0].y, a1);
        a2 = fmaf(xv.x, whi[0].x, a2); a3 = fmaf(xv.x, whi[0].y, a3);
        a0 = fmaf(xv.y, wlo[1].x, a0); a1 = fmaf(xv.y, wlo[1].y, a1);
        a2 = fmaf(xv.y, whi[1].x, a2); a3 = fmaf(xv.y, whi[1].y, a3);
        a0 = fmaf(xv.z, wlo[2].x, a0); a1 = fmaf(xv.z, wlo[2].y, a1);
        a2 = fmaf(xv.z, whi[2].x, a2); a3 = fmaf(xv.z, whi[2].y, a3);
        a0 = fmaf(xv.w, wlo[3].x, a0); a1 = fmaf(xv.w, wlo[3].y, a1);
        a2 = fmaf(xv.w, whi[3].x, a2); a3 = fmaf(xv.w, whi[3].y, a3);
        acc[r][0] = a0; acc[r][1] = a1; acc[r][2] = a2; acc[r][3] = a3;
      }
    }
    __syncthreads();
  }

#pragma unroll
  for (int r = 0; r < 8; ++r) {
    uint2 pv;
    pv.x = packbf(acc[r][0], acc[r][2]);
    pv.y = packbf(acc[r][1], acc[r][3]);
    *reinterpret_cast<uint2*>(&hb[(size_t)(row0 + r0 + r) * 64 + jlo]) = pv;
  }

  float as0 = a_s[jlo], as1 = a_s[jlo + 1], as2 = a_s[jlo + 64], as3 = a_s[jlo + 65];
  float ad0 = a_d[jlo], ad1 = a_d[jlo + 1], ad2 = a_d[jlo + 64], ad3 = a_d[jlo + 65];
  int lane = t & 63;
#pragma unroll
  for (int r = 0; r < 8; ++r) {
    float psa = fmaf(acc[r][0], as0, acc[r][1] * as1);
    float psb = fmaf(acc[r][2], as2, acc[r][3] * as3);
    float pda = fmaf(acc[r][0], ad0, acc[r][1] * ad1);
    float pdb = fmaf(acc[r][2], ad2, acc[r][3] * ad3);
#pragma unroll
    for (int m = 1; m < 16; m <<= 1) {
      psa += __shfl_xor(psa, m); psb += __shfl_xor(psb, m);
      pda += __shfl_xor(pda, m); pdb += __shfl_xor(pdb, m);
    }
    if ((lane & 15) == 0) {
      int hA = (lane >> 4) & 1;
      size_t row = (size_t)(row0 + r0 + r);
      als[row * 4 + hA] = psa; als[row * 4 + hA + 2] = psb;
      ald[row * 4 + hA] = pda; ald[row * 4 + hA + 2] = pdb;
    }
  }
}

// GEMM (K=128, OUT=32) f32 out, fused single-head als/ald.
__global__ __launch_bounds__(256, 2) void gemm32_kernel(
    const float* __restrict__ x, const float* __restrict__ W,
    const float* __restrict__ a_s, const float* __restrict__ a_d,
    float* __restrict__ h, float* __restrict__ als, float* __restrict__ ald)
{
  __shared__ float xs[64 * 128];
  __shared__ float ws[2][32 * 32];
  int t = threadIdx.x;
  int row0 = blockIdx.x * 64;
  {
    const char* xg = (const char*)(x + (size_t)row0 * 128);
    char* xl = (char*)xs;
#pragma unroll
    for (int it = 0; it < 8; ++it)
      async_copy16(xl + it * 4096 + t * 16, xg + it * 4096 + t * 16);
  }
  async_copy16((char*)ws[0] + t * 16, (const char*)W + t * 16);
  __syncthreads();

  int cg = t & 7, rg = t >> 3;
  int r0 = rg * 2, c0 = cg * 4;
  float acc[2][4];
#pragma unroll
  for (int r = 0; r < 2; ++r)
#pragma unroll
    for (int c = 0; c < 4; ++c) acc[r][c] = 0.f;

  for (int ch = 0; ch < 4; ++ch) {
    if (ch < 3) {
      const char* wg = (const char*)W + (size_t)(ch + 1) * 32 * 32 * 4;
      async_copy16((char*)ws[(ch + 1) & 1] + t * 16, wg + t * 16);
    }
    const float* wc = ws[ch & 1];
    const float* xc = xs + ch * 32;
#pragma unroll
    for (int kk = 0; kk < 32; kk += 4) {
      float4 wv[4];
#pragma unroll
      for (int q = 0; q < 4; ++q)
        wv[q] = *reinterpret_cast<const float4*>(&wc[(kk + q) * 32 + c0]);
#pragma unroll
      for (int r = 0; r < 2; ++r) {
        float4 xv = *reinterpret_cast<const float4*>(&xc[(r0 + r) * 128 + kk]);
#pragma unroll
        for (int c = 0; c < 4; ++c) {
          float a = acc[r][c];
          a = fmaf(xv.x, (&wv[0].x)[c], a);
          a = fmaf(xv.y, (&wv[1].x)[c], a);
          a = fmaf(xv.z, (&wv[2].x)[c], a);
          a = fmaf(xv.w, (&wv[3].x)[c], a);
          acc[r][c] = a;
        }
      }
    }
    __syncthreads();
  }

#pragma unroll
  for (int r = 0; r < 2; ++r) {
    float4 hv = make_float4(acc[r][0], acc[r][1], acc[r][2], acc[r][3]);
    *reinterpret_cast<float4*>(&h[(size_t)(row0 + r0 + r) * 32 + c0]) = hv;
  }
  float asv[4], adv[4];
#pragma unroll
  for (int c = 0; c < 4; ++c) { asv[c] = a_s[c0 + c]; adv[c] = a_d[c0 + c]; }
#pragma unroll
  for (int r = 0; r < 2; ++r) {
    float ps = acc[r][0] * asv[0] + acc[r][1] * asv[1] + acc[r][2] * asv[2] + acc[r][3] * asv[3];
    float pd = acc[r][0] * adv[0] + acc[r][1] * adv[1] + acc[r][2] * adv[2] + acc[r][3] * adv[3];
#pragma unroll
    for (int m = 1; m < 8; m <<= 1) { ps += __shfl_xor(ps, m); pd += __shfl_xor(pd, m); }
    if ((t & 7) == 0) {
      als[row0 + r0 + r] = ps;
      ald[row0 + r0 + r] = pd;
    }
  }
}

// Aggregate for OUT=128 (4 heads x 32), packed-bf16 h gather.
// One wave per dst node. Half-wave edge split: lanes 0-31 process edges
// [0,d0), lanes 32-63 process [d0,deg); lane c=lane&31 owns features
// {2c,2c+1,2c+64,2c+65} via one uint2 load per edge; halves combined with
// __shfl_xor(...,32) at the end. Unroll x2 -> 4 row-loads in flight/wave.
__global__ __launch_bounds__(256) void aggregate128_kernel(
    const unsigned* __restrict__ hb, const float* __restrict__ als, const float* __restrict__ ald,
    const int* __restrict__ row_ptr, const int* __restrict__ csr_src,
    const float* __restrict__ bias, const float* __restrict__ ln_g, const float* __restrict__ ln_b,
    float* __restrict__ out, int n)
{
  __shared__ int s_src[4][64];
  __shared__ float s_ex[4][64][4];
  int t = threadIdx.x, lane = t & 63, wid = t >> 6;
  int node = blockIdx.x * 4 + wid;
  if (node >= n) return;
  int start = row_ptr[node], end = row_ptr[node + 1];
  int deg = end - start;

  float4 adq = reinterpret_cast<const float4*>(ald)[node];
  float adl[4] = {adq.x, adq.y, adq.z, adq.w};
  int hi = lane >> 5, c = lane & 31;
  int h0 = c >> 4, h1 = h0 + 2;
  float a0 = 0.f, a1 = 0.f, a2 = 0.f, a3 = 0.f;   // features 2c,2c+1,2c+64,2c+65
  float ssum[4];

  if (deg <= 64) {
    // single-pass softmax: one edge per lane
    bool valid = lane < deg;
    int s = 0;
    if (valid) s = csr_src[start + lane];
    float4 q = reinterpret_cast<const float4*>(als)[s];
    float v[4] = {q.x, q.y, q.z, q.w};
    float mx[4];
#pragma unroll
    for (int hh = 0; hh < 4; ++hh) {
      float w = v[hh] + adl[hh];
      w = w > 0.f ? w : 0.2f * w;
      v[hh] = valid ? w : -INFINITY;
      mx[hh] = v[hh];
    }
#pragma unroll
    for (int hh = 0; hh < 4; ++hh)
#pragma unroll
      for (int m = 1; m < 64; m <<= 1) mx[hh] = fmaxf(mx[hh], __shfl_xor(mx[hh], m));
    float ex[4];
#pragma unroll
    for (int hh = 0; hh < 4; ++hh) {
      ex[hh] = valid ? __expf(v[hh] - mx[hh]) : 0.f;
      ssum[hh] = ex[hh];
    }
#pragma unroll
    for (int hh = 0; hh < 4; ++hh)
#pragma unroll
      for (int m = 1; m < 64; m <<= 1) ssum[hh] += __shfl_xor(ssum[hh], m);

    s_src[wid][lane] = s;
#pragma unroll
    for (int hh = 0; hh < 4; ++hh) s_ex[wid][lane][hh] = ex[hh];

    // half-wave split gather
    int d1 = deg >> 1, d0c = deg - d1;
    int base = hi ? d0c : 0;
    int cnt = hi ? d1 : d0c;
    float b0a = 0.f, b1a = 0.f, b2a = 0.f, b3a = 0.f;
    int j = 0;
    for (; j + 2 <= cnt; j += 2) {
      int sa = s_src[wid][base + j];
      int sb = s_src[wid][base + j + 1];
      uint2 ua = *reinterpret_cast<const uint2*>(&hb[(size_t)sa * 64 + 2 * c]);
      uint2 ub = *reinterpret_cast<const uint2*>(&hb[(size_t)sb * 64 + 2 * c]);
      float wa0 = s_ex[wid][base + j][h0], wa1 = s_ex[wid][base + j][h1];
      float wb0 = s_ex[wid][base + j + 1][h0], wb1 = s_ex[wid][base + j + 1][h1];
      a0 = fmaf(wa0, bflo(ua.x), a0); a1 = fmaf(wa0, bflo(ua.y), a1);
      a2 = fmaf(wa1, bfhi(ua.x), a2); a3 = fmaf(wa1, bfhi(ua.y), a3);
      b0a = fmaf(wb0, bflo(ub.x), b0a); b1a = fmaf(wb0, bflo(ub.y), b1a);
      b2a = fmaf(wb1, bfhi(ub.x), b2a); b3a = fmaf(wb1, bfhi(ub.y), b3a);
    }
    if (j < cnt) {
      int sa = s_src[wid][base + j];
      uint2 ua = *reinterpret_cast<const uint2*>(&hb[(size_t)sa * 64 + 2 * c]);
      float wa0 = s_ex[wid][base + j][h0], wa1 = s_ex[wid][base + j][h1];
      a0 = fmaf(wa0, bflo(ua.x), a0); a1 = fmaf(wa0, bflo(ua.y), a1);
      a2 = fmaf(wa1, bfhi(ua.x), a2); a3 = fmaf(wa1, bfhi(ua.y), a3);
    }
    a0 += b0a; a1 += b1a; a2 += b2a; a3 += b3a;
    // combine halves
    a0 += __shfl_xor(a0, 32); a1 += __shfl_xor(a1, 32);
    a2 += __shfl_xor(a2, 32); a3 += __shfl_xor(a3, 32);
  } else {
    // generic 2-pass fallback (deg > 64: essentially never)
    float mx[4];
#pragma unroll
    for (int hh = 0; hh < 4; ++hh) mx[hh] = -INFINITY;
    for (int eb = start; eb < end; eb += 64) {
      int e = eb + lane;
      if (e < end) {
        int s = csr_src[e];
        float4 q = reinterpret_cast<const float4*>(als)[s];
        float av[4] = {q.x, q.y, q.z, q.w};
#pragma unroll
        for (int hh = 0; hh < 4; ++hh) {
          float v = av[hh] + adl[hh];
          v = v > 0.f ? v : 0.2f * v;
          mx[hh] = fmaxf(mx[hh], v);
        }
      }
    }
#pragma unroll
    for (int hh = 0; hh < 4; ++hh)
#pragma unroll
      for (int m = 1; m < 64; m <<= 1) mx[hh] = fmaxf(mx[hh], __shfl_xor(mx[hh], m));
#pragma unroll
    for (int hh = 0; hh < 4; ++hh) ssum[hh] = 0.f;
    for (int eb = start; eb < end; eb += 64) {
      int e = eb + lane;
      int s = 0;
      float exv[4] = {0.f, 0.f, 0.f, 0.f};
      if (e < end) {
        s = csr_src[e];
        float4 q = reinterpret_cast<const float4*>(als)[s];
        float av[4] = {q.x, q.y, q.z, q.w};
#pragma unroll
        for (int hh = 0; hh < 4; ++hh) {
          float v = av[hh] + adl[hh];
          v = v > 0.f ? v : 0.2f * v;
          exv[hh] = __expf(v - mx[hh]);
          ssum[hh] += exv[hh];
        }
      }
      s_src[wid][lane] = s;
#pragma unroll
      for (int hh = 0; hh < 4; ++hh) s_ex[wid][lane][hh] = exv[hh];
      int cnt = end - eb; if (cnt > 64) cnt = 64;
      for (int j = 0; j < cnt; ++j) {
        int sj = s_src[wid][j];
        uint2 u = *reinterpret_cast<const uint2*>(&hb[(size_t)sj * 64 + 2 * c]);
        float w0 = s_ex[wid][j][h0], w1 = s_ex[wid][j][h1];
        a0 = fmaf(w0, bflo(u.x), a0); a1 = fmaf(w0, bflo(u.y), a1);
        a2 = fmaf(w1, bfhi(u.x), a2); a3 = fmaf(w1, bfhi(u.y), a3);
      }
    }
#pragma unroll
    for (int hh = 0; hh < 4; ++hh)
#pragma unroll
      for (int m = 1; m < 64; m <<= 1) ssum[hh] += __shfl_xor(ssum[hh], m);
    // both halves computed all edges here -> halve
    a0 *= 0.5f; a1 *= 0.5f; a2 *= 0.5f; a3 *= 0.5f;
    a0 += __shfl_xor(a0, 32); a1 += __shfl_xor(a1, 32);
    a2 += __shfl_xor(a2, 32); a3 += __shfl_xor(a3, 32);
  }

  float2 blo = *reinterpret_cast<const float2*>(&bias[2 * c]);
  float2 bhi = *reinterpret_cast<const float2*>(&bias[2 * c + 64]);
  float is0 = 1.f / (ssum[h0] + 1e-16f), is1 = 1.f / (ssum[h1] + 1e-16f);
  float o0 = a0 * is0 + blo.x;
  float o1 = a1 * is0 + blo.y;
  float o2 = a2 * is1 + bhi.x;
  float o3 = a3 * is1 + bhi.y;
  float red = o0 + o1 + o2 + o3;
#pragma unroll
  for (int m = 1; m < 64; m <<= 1) red += __shfl_xor(red, m);
  float mu = red * (1.f / 256.f);   // each feature counted twice across halves
  float d0 = o0 - mu, d1 = o1 - mu, d2 = o2 - mu, d3 = o3 - mu;
  float sq = d0 * d0 + d1 * d1 + d2 * d2 + d3 * d3;
#pragma unroll
  for (int m = 1; m < 64; m <<= 1) sq += __shfl_xor(sq, m);
  float rstd = rsqrtf(sq * (1.f / 256.f) + 1e-5f);
  // this lane writes features (2c+64*hi, 2c+1+64*hi)
  int f = 2 * c + 64 * hi;
  float2 gv = *reinterpret_cast<const float2*>(&ln_g[f]);
  float2 bv = *reinterpret_cast<const float2*>(&ln_b[f]);
  float dx = hi ? d2 : d0, dy = hi ? d3 : d1;
  float2 yv;
  yv.x = eluf(dx * rstd * gv.x + bv.x);
  yv.y = eluf(dy * rstd * gv.y + bv.y);
  *reinterpret_cast<float2*>(&out[(size_t)node * 128 + f]) = yv;
}

// Aggregate for OUT=32 single head (f32 h rows). Half-wave edge split:
// lane c owns feature c; halves process disjoint edges, combined via shfl.
__global__ __launch_bounds__(256) void aggregate32_kernel(
    const float* __restrict__ h, const float* __restrict__ als, const float* __restrict__ ald,
    const int* __restrict__ row_ptr, const int* __restrict__ csr_src,
    const float* __restrict__ bias, const float* __restrict__ ln_g, const float* __restrict__ ln_b,
    float* __restrict__ out, int n)
{
  __shared__ int s_src[4][64];
  __shared__ float s_ex[4][64];
  int t = threadIdx.x, lane = t & 63, wid = t >> 6;
  int node = blockIdx.x * 4 + wid;
  if (node >= n) return;
  int start = row_ptr[node], end = row_ptr[node + 1];
  int deg = end - start;
  float adl = ald[node];
  int hi = lane >> 5, col = lane & 31;
  float acc0 = 0.f, ssum = 0.f;

  if (deg <= 64) {
    bool valid = lane < deg;
    int s = 0;
    if (valid) s = csr_src[start + lane];
    float v = als[s] + adl;
    v = v > 0.f ? v : 0.2f * v;
    v = valid ? v : -INFINITY;
    float mx = v;
#pragma unroll
    for (int m = 1; m < 64; m <<= 1) mx = fmaxf(mx, __shfl_xor(mx, m));
    float ex = valid ? __expf(v - mx) : 0.f;
    ssum = ex;
#pragma unroll
    for (int m = 1; m < 64; m <<= 1) ssum += __shfl_xor(ssum, m);
    s_src[wid][lane] = s;
    s_ex[wid][lane] = ex;

    int d1 = deg >> 1, d0c = deg - d1;
    int base = hi ? d0c : 0;
    int cnt = hi ? d1 : d0c;
    float acc1 = 0.f;
    int j = 0;
    for (; j + 2 <= cnt; j += 2) {
      int sa = s_src[wid][base + j];
      int sb = s_src[wid][base + j + 1];
      float ha = h[(size_t)sa * 32 + col];
      float hbv = h[(size_t)sb * 32 + col];
      acc0 = fmaf(s_ex[wid][base + j], ha, acc0);
      acc1 = fmaf(s_ex[wid][base + j + 1], hbv, acc1);
    }
    if (j < cnt)
      acc0 = fmaf(s_ex[wid][base + j], h[(size_t)s_src[wid][base + j] * 32 + col], acc0);
    acc0 += acc1;
    acc0 += __shfl_xor(acc0, 32);
  } else {
    float mx = -INFINITY;
    for (int eb = start; eb < end; eb += 64) {
      int e = eb + lane;
      if (e < end) {
        float v = als[csr_src[e]] + adl;
        v = v > 0.f ? v : 0.2f * v;
        mx = fmaxf(mx, v);
      }
    }
#pragma unroll
    for (int m = 1; m < 64; m <<= 1) mx = fmaxf(mx, __shfl_xor(mx, m));
    for (int eb = start; eb < end; eb += 64) {
      int e = eb + lane;
      int s = 0; float ex = 0.f;
      if (e < end) {
        s = csr_src[e];
        float v = als[s] + adl;
        v = v > 0.f ? v : 0.2f * v;
        ex = __expf(v - mx);
        ssum += ex;
      }
      s_src[wid][lane] = s;
      s_ex[wid][lane] = ex;
      int cnt = end - eb; if (cnt > 64) cnt = 64;
      for (int j = 0; j < cnt; ++j)
        acc0 = fmaf(s_ex[wid][j], h[(size_t)s_src[wid][j] * 32 + col], acc0);
    }
#pragma unroll
    for (int m = 1; m < 64; m <<= 1) ssum += __shfl_xor(ssum, m);
    acc0 *= 0.5f;
    acc0 += __shfl_xor(acc0, 32);
  }

  float o0 = acc0 / (ssum + 1e-16f) + bias[col];
  float red = o0;
#pragma unroll
  for (int m = 1; m < 64; m <<= 1) red += __shfl_xor(red, m);
  float mu = red * (1.f / 64.f);
  float d0 = o0 - mu;
  float sq = d0 * d0;
#pragma unroll
  for (int m = 1; m < 64; m <<= 1) sq += __shfl_xor(sq, m);
  float rstd = rsqrtf(sq * (1.f / 64.f) + 1e-5f);
  float y0 = d0 * rstd * ln_g[col] + ln_b[col];
  if (lane < 32) out[(size_t)node * 32 + col] = eluf(y0);
}

__device__ __forceinline__ int lower_bound_dev(const int* a, int n, int key) {
  int lo = 0, hi = n;
  while (lo < hi) { int mid = (lo + hi) >> 1; if (a[mid] < key) lo = mid + 1; else hi = mid; }
  return lo;
}

__global__ __launch_bounds__(256) void pool_kernel(const float* __restrict__ x2,
                                                   const int* __restrict__ batch,
                                                   float* __restrict__ hg, int n) {
  int g = blockIdx.x;
  int lo = lower_bound_dev(batch, n, g);
  int hi = lower_bound_dev(batch, n, g + 1);
  int t = threadIdx.x;
  int c = t & 31, r = t >> 5;
  float acc = 0.f;
  for (int i = lo + r; i < hi; i += 8) acc += x2[(size_t)i * 32 + c];
  __shared__ float red[8][32];
  red[r][c] = acc;
  __syncthreads();
  if (r == 0) {
    float s = 0.f;
#pragma unroll
    for (int k = 0; k < 8; ++k) s += red[k][c];
    float cnt = (float)(hi - lo);
    hg[g * 32 + c] = s / fmaxf(cnt, 1.f);
  }
}

__global__ void fc_kernel(const float* __restrict__ hg,
                          const float* __restrict__ fc1w, const float* __restrict__ fc1b,
                          const float* __restrict__ fc2w, const float* __restrict__ fc2b,
                          float* __restrict__ out) {
  int g = threadIdx.x;
  if (g >= NG) return;
  float v[32];
#pragma unroll
  for (int k = 0; k < 32; ++k) v[k] = hg[g * 32 + k];
  float z[16];
#pragma unroll
  for (int j = 0; j < 16; ++j) {
    float a = fc1b[j];
#pragma unroll
    for (int k = 0; k < 32; ++k) a = fmaf(v[k], fc1w[k * 16 + j], a);
    z[j] = fmaxf(a, 0.f);
  }
#pragma unroll
  for (int o = 0; o < 2; ++o) {
    float a = fc2b[o];
#pragma unroll
    for (int j = 0; j < 16; ++j) a = fmaf(z[j], fc2w[j * 2 + o], a);
    out[g * 2 + o] = a;
  }
}

extern "C" void kernel_launch(void* const* d_in, const int* in_sizes, int n_in,
                              void* d_out, int out_size, void* d_ws, size_t ws_size,
                              hipStream_t stream) {
  const float* x    = (const float*)d_in[0];
  const int*   ei   = (const int*)d_in[1];
  const int*   batch= (const int*)d_in[2];
  const float* W0   = (const float*)d_in[3];
  const float* as0  = (const float*)d_in[4];
  const float* ad0  = (const float*)d_in[5];
  const float* b0   = (const float*)d_in[6];
  const float* ln0g = (const float*)d_in[7];
  const float* ln0b = (const float*)d_in[8];
  const float* W1   = (const float*)d_in[9];
  const float* as1  = (const float*)d_in[10];
  const float* ad1  = (const float*)d_in[11];
  const float* b1   = (const float*)d_in[12];
  const float* ln1g = (const float*)d_in[13];
  const float* ln1b = (const float*)d_in[14];
  const float* W2   = (const float*)d_in[15];
  const float* as2  = (const float*)d_in[16];
  const float* ad2  = (const float*)d_in[17];
  const float* b2   = (const float*)d_in[18];
  const float* ln2g = (const float*)d_in[19];
  const float* ln2b = (const float*)d_in[20];
  const float* fc1w = (const float*)d_in[21];
  const float* fc1b = (const float*)d_in[22];
  const float* fc2w = (const float*)d_in[23];
  const float* fc2b = (const float*)d_in[24];
  float* out = (float*)d_out;

  const int* srce = ei;
  const int* dste = ei + EE;

  unsigned* hb = (unsigned*)d_ws;            // N*64 packed bf16 pairs
  float* B2  = (float*)(hb + (size_t)NN * 64); // N*128
  float* als = B2 + (size_t)NN * 128;        // N*4
  float* ald = als + (size_t)NN * 4;         // N*4
  float* h2  = ald + (size_t)NN * 4;         // N*32
  float* x2  = h2 + (size_t)NN * 32;         // N*32
  float* hg  = x2 + (size_t)NN * 32;         // 64*32
  int* deg      = (int*)(hg + NG * 32);      // N
  int* row_ptr  = deg + NN;                  // N+1
  int* cursor   = row_ptr + NN + 1;          // N
  int* csr_src  = cursor + NN;               // E
  int* bsum     = csr_src + EE;              // SCAN_BLOCKS
  int* boff     = bsum + SCAN_BLOCKS;        // SCAN_BLOCKS

  // CSR build (shared by all 3 layers)
  zero_int_kernel<<<(NN + 255) / 256, 256, 0, stream>>>(deg, NN);
  count_deg_kernel<<<(EE + 255) / 256, 256, 0, stream>>>(dste, deg, EE);
  scanA_kernel<<<SCAN_BLOCKS, 1024, 0, stream>>>(deg, row_ptr, bsum, NN);
  scanB_kernel<<<1, 64, 0, stream>>>(bsum, boff, SCAN_BLOCKS);
  scanC_kernel<<<SCAN_BLOCKS, 1024, 0, stream>>>(row_ptr, boff, cursor, NN);
  scatter_kernel<<<(EE + 255) / 256, 256, 0, stream>>>(srce, dste, cursor, csr_src, EE);

  // layer 0
  gemm128_kernel<<<625, 256, 0, stream>>>(x, W0, as0, ad0, hb, als, ald);
  aggregate128_kernel<<<(NN + 3) / 4, 256, 0, stream>>>(hb, als, ald, row_ptr, csr_src,
                                                        b0, ln0g, ln0b, B2, NN);
  // layer 1
  gemm128_kernel<<<625, 256, 0, stream>>>(B2, W1, as1, ad1, hb, als, ald);
  aggregate128_kernel<<<(NN + 3) / 4, 256, 0, stream>>>(hb, als, ald, row_ptr, csr_src,
                                                        b1, ln1g, ln1b, B2, NN);
  // layer 2
  gemm32_kernel<<<625, 256, 0, stream>>>(B2, W2, as2, ad2, h2, als, ald);
  aggregate32_kernel<<<(NN + 3) / 4, 256, 0, stream>>>(h2, als, ald, row_ptr, csr_src,
                                                       b2, ln2g, ln2b, x2, NN);
  // pool + classifier
  pool_kernel<<<NG, 256, 0, stream>>>(x2, batch, hg, NN);
  fc_kernel<<<1, 64, 0, stream>>>(hg, fc1w, fc1b, fc2w, fc2b, out);
}